// Round 4
// baseline (321.688 us; speedup 1.0000x reference)
//
#include <hip/hip_runtime.h>
#include <stdint.h>

typedef unsigned short u16;
typedef __attribute__((ext_vector_type(8))) short bf16x8;
typedef __attribute__((ext_vector_type(4))) float f32x4;
typedef __attribute__((ext_vector_type(4))) unsigned short u16x4;

#define DEVI static __device__ __forceinline__

// dots*scale folded into Q, with base-2 softmax: exp(s) == exp2(s*log2e)
#define QSCALE (0.125f * 1.4426950408889634f)

DEVI u16 f2bf(float f) {
  union { float f; unsigned int u; } v; v.f = f;
  unsigned int u = v.u + 0x7fffu + ((v.u >> 16) & 1u);
  return (u16)(u >> 16);
}
DEVI float bf2f(u16 h) {
  union { unsigned int u; float f; } v; v.u = ((unsigned int)h) << 16;
  return v.f;
}
DEVI void gl16(const void* g, void* l) {
  __builtin_amdgcn_global_load_lds(
      (__attribute__((address_space(1))) void*)g,
      (__attribute__((address_space(3))) void*)l, 16, 0, 0);
}
// packed f32x2 -> bf16x2 (RNE), lo=bf16(a), hi=bf16(b)
DEVI unsigned int cvtpk(float a, float b) {
  unsigned int r;
  asm("v_cvt_pk_bf16_f32 %0, %1, %2" : "=v"(r) : "v"(a), "v"(b));
  return r;
}

// ---------------- K1: LayerNorm (hi only; QKV GEMM is 2-product) ----------------
__global__ __launch_bounds__(256) void k_ln_split(
    const float* __restrict__ x, const float* __restrict__ gamma,
    const float* __restrict__ beta, u16* __restrict__ xh) {
  const int row = blockIdx.x;          // 8192 rows
  const int t = threadIdx.x;           // 256 threads, 4 floats each
  const float4* xr = (const float4*)(x + (size_t)row * 1024);
  float4 v = xr[t];
  float s = v.x + v.y + v.z + v.w;
  float s2 = v.x * v.x + v.y * v.y + v.z * v.z + v.w * v.w;
  #pragma unroll
  for (int m = 1; m < 64; m <<= 1) { s += __shfl_xor(s, m); s2 += __shfl_xor(s2, m); }
  __shared__ float ls[4], ls2[4];
  if ((t & 63) == 0) { ls[t >> 6] = s; ls2[t >> 6] = s2; }
  __syncthreads();
  s = ls[0] + ls[1] + ls[2] + ls[3];
  s2 = ls2[0] + ls2[1] + ls2[2] + ls2[3];
  float mu = s * (1.0f / 1024.0f);
  float var = s2 * (1.0f / 1024.0f) - mu * mu;
  float rstd = rsqrtf(var + 1e-5f);
  float4 g = ((const float4*)gamma)[t];
  float4 b = ((const float4*)beta)[t];
  float xv[4] = {v.x, v.y, v.z, v.w};
  float gg[4] = {g.x, g.y, g.z, g.w};
  float bb[4] = {b.x, b.y, b.z, b.w};
  u16x4 hv;
  #pragma unroll
  for (int i = 0; i < 4; i++) {
    float xn = (xv[i] - mu) * rstd * gg[i] + bb[i];
    hv[i] = f2bf(xn);
  }
  ((u16x4*)xh)[(size_t)row * 256 + t] = hv;
}

// ---------------- K1b: transpose + hi/lo split of weights ----------------
// W [K][N] fp32  ->  Wt hi/lo [N][K] bf16
__global__ __launch_bounds__(256) void k_wsplit_t(
    const float* __restrict__ W, u16* __restrict__ Wth, u16* __restrict__ Wtl,
    int K, int N) {
  __shared__ float tile[32][33];
  const int t = threadIdx.x;
  const int tx = t & 31, ty = t >> 5;  // ty in 0..7
  #pragma unroll
  for (int i = 0; i < 4; i++) {
    int k = blockIdx.y * 32 + ty + i * 8;
    int n = blockIdx.x * 32 + tx;
    tile[ty + i * 8][tx] = W[(size_t)k * N + n];
  }
  __syncthreads();
  #pragma unroll
  for (int i = 0; i < 4; i++) {
    int n = blockIdx.x * 32 + ty + i * 8;   // output row
    int k = blockIdx.y * 32 + tx;           // output col
    float v = tile[tx][ty + i * 8];
    size_t o = (size_t)n * K + k;
    u16 hi = f2bf(v);
    Wth[o] = hi; Wtl[o] = f2bf(v - bf2f(hi));
  }
}

// ---------------- K2/K4: GEMM (m97 structure) ----------------
// C[M x N] = A[M x 1024] * Bt[N x 1024]^T.
// MODE 0: A hi only, B hi/lo (2 products). Epilogue scatters Q(scaled),K,Vt bf16.
// MODE 1: A hi/lo, B hi/lo (3 products). Epilogue +bias, fp32 store.
template <int MODE>
__global__ __launch_bounds__(256) void k_gemm(
    const u16* __restrict__ Ah, const u16* __restrict__ Al,
    const u16* __restrict__ Bh, const u16* __restrict__ Bl,
    u16* __restrict__ Qh, u16* __restrict__ Kh, u16* __restrict__ Vth,
    float* __restrict__ Cout, const float* __restrict__ bias) {
  __shared__ u16 sAh[128 * 32], sBh[128 * 32], sBl[128 * 32];
  __shared__ u16 sAl[MODE == 1 ? 128 * 32 : 1];
  const int t = threadIdx.x, lane = t & 63, w = t >> 6;
  const int bm = blockIdx.x, bn = blockIdx.y;
  const int wm = (w >> 1) * 64, wn = (w & 1) * 64;
  const int g = lane >> 4, c = lane & 15;
  const size_t arow0 = (size_t)bm * 128, brow0 = (size_t)bn * 128;

  f32x4 acc[4][4] = {};

  for (int kt = 0; kt < 32; kt++) {
    __syncthreads();
    #pragma unroll
    for (int i = 0; i < 2; i++) {
      int ci = t + i * 256;              // 512 chunks of 16B per tile
      int r = ci >> 2, cc = ci & 3;
      size_t ka = (size_t)kt * 32 + cc * 8;
      gl16(Ah + (arow0 + r) * 1024 + ka, sAh + (size_t)ci * 8);
      gl16(Bh + (brow0 + r) * 1024 + ka, sBh + (size_t)ci * 8);
      gl16(Bl + (brow0 + r) * 1024 + ka, sBl + (size_t)ci * 8);
      if (MODE == 1) gl16(Al + (arow0 + r) * 1024 + ka, sAl + (size_t)ci * 8);
    }
    __syncthreads();
    bf16x8 afh[4], afl[4], bfh[4], bfl[4];
    #pragma unroll
    for (int mi = 0; mi < 4; mi++) {
      int off = (wm + mi * 16 + c) * 32 + g * 8;
      afh[mi] = *(const bf16x8*)(sAh + off);
      if (MODE == 1) afl[mi] = *(const bf16x8*)(sAl + off);
    }
    #pragma unroll
    for (int ni = 0; ni < 4; ni++) {
      int off = (wn + ni * 16 + c) * 32 + g * 8;
      bfh[ni] = *(const bf16x8*)(sBh + off);
      bfl[ni] = *(const bf16x8*)(sBl + off);
    }
    #pragma unroll
    for (int mi = 0; mi < 4; mi++)
      #pragma unroll
      for (int ni = 0; ni < 4; ni++) {
        acc[mi][ni] = __builtin_amdgcn_mfma_f32_16x16x32_bf16(afh[mi], bfh[ni], acc[mi][ni], 0, 0, 0);
        acc[mi][ni] = __builtin_amdgcn_mfma_f32_16x16x32_bf16(afh[mi], bfl[ni], acc[mi][ni], 0, 0, 0);
        if (MODE == 1)
          acc[mi][ni] = __builtin_amdgcn_mfma_f32_16x16x32_bf16(afl[mi], bfh[ni], acc[mi][ni], 0, 0, 0);
      }
  }

  if (MODE == 0) {
    #pragma unroll
    for (int mi = 0; mi < 4; mi++) {
      int grow0 = bm * 128 + wm + mi * 16 + g * 4;   // m = b*2048+s
      int b = grow0 >> 11, s0 = grow0 & 2047;
      #pragma unroll
      for (int ni = 0; ni < 4; ni++) {
        int gcol = bn * 128 + wn + ni * 16 + c;       // n in [0,3072)
        int which = gcol >> 10, rem = gcol & 1023;
        int hh = rem >> 6, dd = rem & 63;
        if (which == 2) {                              // V -> transposed [B,H,Dh,S]
          u16x4 hv;
          #pragma unroll
          for (int r = 0; r < 4; r++) hv[r] = f2bf(acc[mi][ni][r]);
          size_t off = ((size_t)((b * 16 + hh) * 64 + dd)) * 2048 + s0;
          *(u16x4*)(Vth + off) = hv;
        } else {                                       // Q or K -> [B,H,S,Dh]
          u16* dh = which ? Kh : Qh;
          float sc = which ? 1.0f : QSCALE;
          #pragma unroll
          for (int r = 0; r < 4; r++) {
            size_t off = ((size_t)(b * 16 + hh) * 2048 + (s0 + r)) * 64 + dd;
            dh[off] = f2bf(acc[mi][ni][r] * sc);
          }
        }
      }
    }
  } else {
    #pragma unroll
    for (int mi = 0; mi < 4; mi++) {
      int grow0 = bm * 128 + wm + mi * 16 + g * 4;
      #pragma unroll
      for (int ni = 0; ni < 4; ni++) {
        int gcol = bn * 128 + wn + ni * 16 + c;
        float bb = bias[gcol];
        #pragma unroll
        for (int r = 0; r < 4; r++)
          Cout[(size_t)(grow0 + r) * 1024 + gcol] = acc[mi][ni][r] + bb;
      }
    }
  }
}

// ---------------- K3: block-causal flash attention (v4) ----------------
// grid (64 b*h, 8); each block processes paired q-tiles {15-y, y}: exactly 36
// kv-tiles per block -> 512 uniform blocks = 2/CU, no tail.
// Common path has ZERO cross-lane reduction ops: lane-local defer-max check
// (register compare + __all) and per-lane partial lrun (reduced once at end).
__global__ __launch_bounds__(256) void k_attn(
    const u16* __restrict__ Qh, const u16* __restrict__ Kh,
    const u16* __restrict__ Vth,
    u16* __restrict__ Oh, u16* __restrict__ Ol) {
  __shared__ u16 lK[2][64 * 64], lV[2][64 * 64];
  __shared__ u16 lP[4 * 2048];                        // 4 waves x [32][64]
  const int t = threadIdx.x, lane = t & 63, w = t >> 6;
  const int bh = blockIdx.x;             // 0..63
  const int b = bh >> 4, h = bh & 15;
  const int g = lane >> 4, c = lane & 15;

  const u16* Kb = Kh + (size_t)bh * 2048 * 64;
  const u16* Vb = Vth + (size_t)bh * 64 * 2048;
  u16* pb = lP + w * 2048;

  // staging: K [64 kv][64 d], Vt [64 d][64 kv]; source pre-swizzled (XOR by row)
  const int ci0 = t, ci1 = t + 256;
  const int r0 = ci0 >> 3, cc0 = ci0 & 7;
  const int r1 = ci1 >> 3, cc1 = ci1 & 7;
  const int cs0 = cc0 ^ (r0 & 7), cs1 = cc1 ^ (r1 & 7);

  for (int half = 0; half < 2; half++) {
    const int qt = half ? blockIdx.y : 15 - blockIdx.y;  // long tile first
    const int qrow0 = qt * 128;
    const int ntiles = ((qt >> 1) + 1) * 4;

    // Q fragments for this wave's 32 rows, k = Dh in two 32-steps
    bf16x8 qf[2][2];
    {
      const u16* qb = Qh + ((size_t)bh * 2048 + qrow0 + w * 32) * 64;
      #pragma unroll
      for (int mi = 0; mi < 2; mi++)
        #pragma unroll
        for (int ks = 0; ks < 2; ks++)
          qf[mi][ks] = *(const bf16x8*)(qb + (size_t)(mi * 16 + c) * 64 + ks * 32 + g * 8);
    }

    float mrun[2][4], lrun[2][4];
    f32x4 o[2][4] = {};
    #pragma unroll
    for (int mi = 0; mi < 2; mi++)
      #pragma unroll
      for (int r = 0; r < 4; r++) { mrun[mi][r] = -INFINITY; lrun[mi][r] = 0.f; }

    // prologue: stage tile 0 into buffer 0 (prior half's trailing barrier
    // guarantees all waves are done reading the buffers)
    gl16(Kb + (size_t)r0 * 64 + cs0 * 8, lK[0] + (size_t)ci0 * 8);
    gl16(Vb + (size_t)r0 * 2048 + cs0 * 8, lV[0] + (size_t)ci0 * 8);
    gl16(Kb + (size_t)r1 * 64 + cs1 * 8, lK[0] + (size_t)ci1 * 8);
    gl16(Vb + (size_t)r1 * 2048 + cs1 * 8, lV[0] + (size_t)ci1 * 8);
    __syncthreads();

    for (int kt = 0; kt < ntiles; kt++) {
      const int cur = kt & 1, nxt = cur ^ 1;
      if (kt + 1 < ntiles) {             // prefetch next tile across compute
        const size_t kv0 = (size_t)(kt + 1) * 64;
        gl16(Kb + (kv0 + r0) * 64 + cs0 * 8, lK[nxt] + (size_t)ci0 * 8);
        gl16(Vb + (size_t)r0 * 2048 + kv0 + cs0 * 8, lV[nxt] + (size_t)ci0 * 8);
        gl16(Kb + (kv0 + r1) * 64 + cs1 * 8, lK[nxt] + (size_t)ci1 * 8);
        gl16(Vb + (size_t)r1 * 2048 + kv0 + cs1 * 8, lV[nxt] + (size_t)ci1 * 8);
      }

      // scores: S[32 x 64] = Qs * K^T
      f32x4 s[2][4] = {};
      __builtin_amdgcn_s_setprio(1);
      #pragma unroll
      for (int ni = 0; ni < 4; ni++) {
        int kr = ni * 16 + c;
        #pragma unroll
        for (int ks = 0; ks < 2; ks++) {
          int off = kr * 64 + ((ks * 4 + g) ^ (kr & 7)) * 8;
          bf16x8 kf = *(const bf16x8*)(lK[cur] + off);
          #pragma unroll
          for (int mi = 0; mi < 2; mi++)
            s[mi][ni] = __builtin_amdgcn_mfma_f32_16x16x32_bf16(qf[mi][ks], kf, s[mi][ni], 0, 0, 0);
        }
      }
      __builtin_amdgcn_s_setprio(0);

      // defer-max: lane-local check, no cross-lane ops on the common path
      float tl[2][4];
      #pragma unroll
      for (int mi = 0; mi < 2; mi++)
        #pragma unroll
        for (int r = 0; r < 4; r++)
          tl[mi][r] = fmaxf(fmaxf(s[mi][0][r], s[mi][1][r]), fmaxf(s[mi][2][r], s[mi][3][r]));
      float dmax = -INFINITY;
      #pragma unroll
      for (int mi = 0; mi < 2; mi++)
        #pragma unroll
        for (int r = 0; r < 4; r++)
          dmax = fmaxf(dmax, tl[mi][r] - mrun[mi][r]);
      if (!__all(dmax <= 8.0f)) {        // rare: first tile or large max jump
        #pragma unroll
        for (int m = 1; m < 16; m <<= 1)
          #pragma unroll
          for (int mi = 0; mi < 2; mi++)
            #pragma unroll
            for (int r = 0; r < 4; r++)
              tl[mi][r] = fmaxf(tl[mi][r], __shfl_xor(tl[mi][r], m));
        #pragma unroll
        for (int mi = 0; mi < 2; mi++)
          #pragma unroll
          for (int r = 0; r < 4; r++) {
            float mnew = fmaxf(mrun[mi][r], tl[mi][r]);
            float al = exp2f(mrun[mi][r] - mnew);
            mrun[mi][r] = mnew;
            lrun[mi][r] *= al;
            #pragma unroll
            for (int di = 0; di < 4; di++) o[mi][di][r] *= al;
          }
      }
      // p = exp2(s - m); lrun accumulates per-lane partials (4 cols/lane)
      #pragma unroll
      for (int mi = 0; mi < 2; mi++)
        #pragma unroll
        for (int ni = 0; ni < 4; ni++)
          #pragma unroll
          for (int r = 0; r < 4; r++)
            s[mi][ni][r] = exp2f(s[mi][ni][r] - mrun[mi][r]);
      #pragma unroll
      for (int mi = 0; mi < 2; mi++)
        #pragma unroll
        for (int r = 0; r < 4; r++)
          lrun[mi][r] += (s[mi][0][r] + s[mi][1][r]) + (s[mi][2][r] + s[mi][3][r]);

      // P -> wave-private LDS (bf16 via cvt_pk, XOR-swizzled both sides)
      #pragma unroll
      for (int mi = 0; mi < 2; mi++)
        #pragma unroll
        for (int ni = 0; ni < 4; ni++)
          #pragma unroll
          for (int rp = 0; rp < 2; rp++) {
            unsigned int pk = cvtpk(s[mi][ni][2 * rp], s[mi][ni][2 * rp + 1]);
            int row0 = mi * 16 + g * 4 + 2 * rp;
            int colb = (ni * 16 + c) * 2;
            *(u16*)((char*)pb + ((row0 * 128 + colb) ^ ((row0 & 7) << 4))) = (u16)pk;
            *(u16*)((char*)pb + (((row0 + 1) * 128 + colb) ^ (((row0 + 1) & 7) << 4))) = (u16)(pk >> 16);
          }

      // PV: O += P * V
      bf16x8 pa[2][2];
      #pragma unroll
      for (int mi = 0; mi < 2; mi++)
        #pragma unroll
        for (int ks = 0; ks < 2; ks++) {
          int row = mi * 16 + c;
          pa[mi][ks] = *(const bf16x8*)((char*)pb + ((row * 128 + (ks * 4 + g) * 16) ^ ((row & 7) << 4)));
        }
      __builtin_amdgcn_s_setprio(1);
      #pragma unroll
      for (int di = 0; di < 4; di++) {
        int vr = di * 16 + c;
        #pragma unroll
        for (int ks = 0; ks < 2; ks++) {
          int off = vr * 64 + ((ks * 4 + g) ^ (vr & 7)) * 8;
          bf16x8 vf = *(const bf16x8*)(lV[cur] + off);
          #pragma unroll
          for (int mi = 0; mi < 2; mi++)
            o[mi][di] = __builtin_amdgcn_mfma_f32_16x16x32_bf16(pa[mi][ks], vf, o[mi][di], 0, 0, 0);
        }
      }
      __builtin_amdgcn_s_setprio(0);

      // drains the prefetch and fences buffer reuse + lP
      __syncthreads();
    }

    // epilogue: reduce lrun across the 16-lane row group (once per q-tile)
    #pragma unroll
    for (int m = 1; m < 16; m <<= 1)
      #pragma unroll
      for (int mi = 0; mi < 2; mi++)
        #pragma unroll
        for (int r = 0; r < 4; r++)
          lrun[mi][r] += __shfl_xor(lrun[mi][r], m);
    #pragma unroll
    for (int mi = 0; mi < 2; mi++)
      #pragma unroll
      for (int r = 0; r < 4; r++) {
        float inv = 1.0f / lrun[mi][r];
        int srow = qrow0 + w * 32 + mi * 16 + g * 4 + r;
        size_t rowo = ((size_t)b * 2048 + srow) * 1024 + h * 64;
        #pragma unroll
        for (int di = 0; di < 4; di++) {
          float v = o[mi][di][r] * inv;
          u16 hi = f2bf(v);
          Oh[rowo + di * 16 + c] = hi;
          Ol[rowo + di * 16 + c] = f2bf(v - bf2f(hi));
        }
      }
  }
}

// ---------------- launch ----------------
extern "C" void kernel_launch(void* const* d_in, const int* in_sizes, int n_in,
                              void* d_out, int out_size, void* d_ws, size_t ws_size,
                              hipStream_t stream) {
  const float* x     = (const float*)d_in[0];
  const float* gamma = (const float*)d_in[1];
  const float* beta  = (const float*)d_in[2];
  const float* Wqkv  = (const float*)d_in[3];
  const float* Wout  = (const float*)d_in[4];
  const float* bout  = (const float*)d_in[5];
  float* out = (float*)d_out;

  char* ws = (char*)d_ws;
  size_t off = 0;
  auto alloc = [&](size_t bytes) { char* p = ws + off; off += (bytes + 255) & ~(size_t)255; return p; };
  const size_t SZ_XN = (size_t)8192 * 1024 * 2;         // 16MB
  const size_t SZ_WQ = (size_t)3072 * 1024 * 2;         // 6MB
  const size_t SZ_WO = (size_t)1024 * 1024 * 2;         // 2MB
  const size_t SZ_QKV = (size_t)4 * 16 * 2048 * 64 * 2; // 16MB
  u16* xnh  = (u16*)alloc(SZ_XN);   // also attnout-hi after attention
  u16* xnl  = (u16*)alloc(SZ_XN);   // attnout-lo (written by k_attn)
  u16* wqth = (u16*)alloc(SZ_WQ);
  u16* wqtl = (u16*)alloc(SZ_WQ);
  u16* woth = (u16*)alloc(SZ_WO);
  u16* wotl = (u16*)alloc(SZ_WO);
  u16* Qh  = (u16*)alloc(SZ_QKV);
  u16* Kh  = (u16*)alloc(SZ_QKV);
  u16* Vth = (u16*)alloc(SZ_QKV);
  if (off > ws_size) return;  // workspace too small -> fail visibly (poisoned out)

  k_ln_split<<<8192, 256, 0, stream>>>(x, gamma, beta, xnh);
  k_wsplit_t<<<dim3(96, 32), 256, 0, stream>>>(Wqkv, wqth, wqtl, 1024, 3072);
  k_wsplit_t<<<dim3(32, 32), 256, 0, stream>>>(Wout, woth, wotl, 1024, 1024);
  k_gemm<0><<<dim3(64, 24), 256, 0, stream>>>(xnh, nullptr, wqth, wqtl,
                                              Qh, Kh, Vth, nullptr, nullptr);
  // attnout (hi/lo) reuses the xn buffers (xn is dead after the QKV GEMM)
  k_attn<<<dim3(64, 8), 256, 0, stream>>>(Qh, Kh, Vth, xnh, xnl);
  k_gemm<1><<<dim3(64, 8), 256, 0, stream>>>(xnh, xnl, woth, wotl,
                                             nullptr, nullptr, nullptr,
                                             out, bout);
}

// Round 5
// 256.757 us; speedup vs baseline: 1.2529x; 1.2529x over previous
//
#include <hip/hip_runtime.h>
#include <stdint.h>

typedef unsigned short u16;
typedef __attribute__((ext_vector_type(8))) short bf16x8;
typedef __attribute__((ext_vector_type(4))) float f32x4;
typedef __attribute__((ext_vector_type(4))) unsigned short u16x4;
typedef __attribute__((ext_vector_type(4))) unsigned int u32x4;

#define DEVI static __device__ __forceinline__

// dots*scale folded into Q, with base-2 softmax: exp(s) == exp2(s*log2e)
#define QSCALE (0.125f * 1.4426950408889634f)

DEVI u16 f2bf(float f) {
  union { float f; unsigned int u; } v; v.f = f;
  unsigned int u = v.u + 0x7fffu + ((v.u >> 16) & 1u);
  return (u16)(u >> 16);
}
DEVI float bf2f(u16 h) {
  union { unsigned int u; float f; } v; v.u = ((unsigned int)h) << 16;
  return v.f;
}
DEVI void gl16(const void* g, void* l) {
  __builtin_amdgcn_global_load_lds(
      (__attribute__((address_space(1))) void*)g,
      (__attribute__((address_space(3))) void*)l, 16, 0, 0);
}
// packed f32x2 -> bf16x2 (RNE), lo=bf16(a), hi=bf16(b)
DEVI unsigned int cvtpk(float a, float b) {
  unsigned int r;
  asm("v_cvt_pk_bf16_f32 %0, %1, %2" : "=v"(r) : "v"(a), "v"(b));
  return r;
}

// ---------------- K1: LayerNorm (hi only; QKV GEMM is 2-product) ----------------
__global__ __launch_bounds__(256) void k_ln_split(
    const float* __restrict__ x, const float* __restrict__ gamma,
    const float* __restrict__ beta, u16* __restrict__ xh) {
  const int row = blockIdx.x;          // 8192 rows
  const int t = threadIdx.x;           // 256 threads, 4 floats each
  const float4* xr = (const float4*)(x + (size_t)row * 1024);
  float4 v = xr[t];
  float s = v.x + v.y + v.z + v.w;
  float s2 = v.x * v.x + v.y * v.y + v.z * v.z + v.w * v.w;
  #pragma unroll
  for (int m = 1; m < 64; m <<= 1) { s += __shfl_xor(s, m); s2 += __shfl_xor(s2, m); }
  __shared__ float ls[4], ls2[4];
  if ((t & 63) == 0) { ls[t >> 6] = s; ls2[t >> 6] = s2; }
  __syncthreads();
  s = ls[0] + ls[1] + ls[2] + ls[3];
  s2 = ls2[0] + ls2[1] + ls2[2] + ls2[3];
  float mu = s * (1.0f / 1024.0f);
  float var = s2 * (1.0f / 1024.0f) - mu * mu;
  float rstd = rsqrtf(var + 1e-5f);
  float4 g = ((const float4*)gamma)[t];
  float4 b = ((const float4*)beta)[t];
  float xv[4] = {v.x, v.y, v.z, v.w};
  float gg[4] = {g.x, g.y, g.z, g.w};
  float bb[4] = {b.x, b.y, b.z, b.w};
  u16x4 hv;
  #pragma unroll
  for (int i = 0; i < 4; i++) {
    float xn = (xv[i] - mu) * rstd * gg[i] + bb[i];
    hv[i] = f2bf(xn);
  }
  ((u16x4*)xh)[(size_t)row * 256 + t] = hv;
}

// ---------------- K1b: transpose + hi/lo split of weights ----------------
// W [K][N] fp32  ->  Wt hi/lo [N][K] bf16
__global__ __launch_bounds__(256) void k_wsplit_t(
    const float* __restrict__ W, u16* __restrict__ Wth, u16* __restrict__ Wtl,
    int K, int N) {
  __shared__ float tile[32][33];
  const int t = threadIdx.x;
  const int tx = t & 31, ty = t >> 5;  // ty in 0..7
  #pragma unroll
  for (int i = 0; i < 4; i++) {
    int k = blockIdx.y * 32 + ty + i * 8;
    int n = blockIdx.x * 32 + tx;
    tile[ty + i * 8][tx] = W[(size_t)k * N + n];
  }
  __syncthreads();
  #pragma unroll
  for (int i = 0; i < 4; i++) {
    int n = blockIdx.x * 32 + ty + i * 8;   // output row
    int k = blockIdx.y * 32 + tx;           // output col
    float v = tile[tx][ty + i * 8];
    size_t o = (size_t)n * K + k;
    u16 hi = f2bf(v);
    Wth[o] = hi; Wtl[o] = f2bf(v - bf2f(hi));
  }
}

// ---------------- K2/K4: GEMM (m97 structure) ----------------
// C[M x N] = A[M x 1024] * Bt[N x 1024]^T.
// MODE 0: A hi only, B hi/lo (2 products). Epilogue scatters Q(scaled),K,Vt bf16.
// MODE 1: A hi/lo, B hi/lo (3 products). Epilogue +bias, fp32 store.
template <int MODE>
__global__ __launch_bounds__(256) void k_gemm(
    const u16* __restrict__ Ah, const u16* __restrict__ Al,
    const u16* __restrict__ Bh, const u16* __restrict__ Bl,
    u16* __restrict__ Qh, u16* __restrict__ Kh, u16* __restrict__ Vth,
    float* __restrict__ Cout, const float* __restrict__ bias) {
  __shared__ u16 sAh[128 * 32], sBh[128 * 32], sBl[128 * 32];
  __shared__ u16 sAl[MODE == 1 ? 128 * 32 : 1];
  const int t = threadIdx.x, lane = t & 63, w = t >> 6;
  const int bm = blockIdx.x, bn = blockIdx.y;
  const int wm = (w >> 1) * 64, wn = (w & 1) * 64;
  const int g = lane >> 4, c = lane & 15;
  const size_t arow0 = (size_t)bm * 128, brow0 = (size_t)bn * 128;

  f32x4 acc[4][4] = {};

  for (int kt = 0; kt < 32; kt++) {
    __syncthreads();
    #pragma unroll
    for (int i = 0; i < 2; i++) {
      int ci = t + i * 256;              // 512 chunks of 16B per tile
      int r = ci >> 2, cc = ci & 3;
      size_t ka = (size_t)kt * 32 + cc * 8;
      gl16(Ah + (arow0 + r) * 1024 + ka, sAh + (size_t)ci * 8);
      gl16(Bh + (brow0 + r) * 1024 + ka, sBh + (size_t)ci * 8);
      gl16(Bl + (brow0 + r) * 1024 + ka, sBl + (size_t)ci * 8);
      if (MODE == 1) gl16(Al + (arow0 + r) * 1024 + ka, sAl + (size_t)ci * 8);
    }
    __syncthreads();
    bf16x8 afh[4], afl[4], bfh[4], bfl[4];
    #pragma unroll
    for (int mi = 0; mi < 4; mi++) {
      int off = (wm + mi * 16 + c) * 32 + g * 8;
      afh[mi] = *(const bf16x8*)(sAh + off);
      if (MODE == 1) afl[mi] = *(const bf16x8*)(sAl + off);
    }
    #pragma unroll
    for (int ni = 0; ni < 4; ni++) {
      int off = (wn + ni * 16 + c) * 32 + g * 8;
      bfh[ni] = *(const bf16x8*)(sBh + off);
      bfl[ni] = *(const bf16x8*)(sBl + off);
    }
    #pragma unroll
    for (int mi = 0; mi < 4; mi++)
      #pragma unroll
      for (int ni = 0; ni < 4; ni++) {
        acc[mi][ni] = __builtin_amdgcn_mfma_f32_16x16x32_bf16(afh[mi], bfh[ni], acc[mi][ni], 0, 0, 0);
        acc[mi][ni] = __builtin_amdgcn_mfma_f32_16x16x32_bf16(afh[mi], bfl[ni], acc[mi][ni], 0, 0, 0);
        if (MODE == 1)
          acc[mi][ni] = __builtin_amdgcn_mfma_f32_16x16x32_bf16(afl[mi], bfh[ni], acc[mi][ni], 0, 0, 0);
      }
  }

  if (MODE == 0) {
    #pragma unroll
    for (int mi = 0; mi < 4; mi++) {
      int grow0 = bm * 128 + wm + mi * 16 + g * 4;   // m = b*2048+s
      int b = grow0 >> 11, s0 = grow0 & 2047;
      #pragma unroll
      for (int ni = 0; ni < 4; ni++) {
        int gcol = bn * 128 + wn + ni * 16 + c;       // n in [0,3072)
        int which = gcol >> 10, rem = gcol & 1023;
        int hh = rem >> 6, dd = rem & 63;
        if (which == 2) {                              // V -> transposed [B,H,Dh,S]
          u16x4 hv;
          #pragma unroll
          for (int r = 0; r < 4; r++) hv[r] = f2bf(acc[mi][ni][r]);
          size_t off = ((size_t)((b * 16 + hh) * 64 + dd)) * 2048 + s0;
          *(u16x4*)(Vth + off) = hv;
        } else {                                       // Q or K -> [B,H,S,Dh]
          u16* dh = which ? Kh : Qh;
          float sc = which ? 1.0f : QSCALE;
          #pragma unroll
          for (int r = 0; r < 4; r++) {
            size_t off = ((size_t)(b * 16 + hh) * 2048 + (s0 + r)) * 64 + dd;
            dh[off] = f2bf(acc[mi][ni][r] * sc);
          }
        }
      }
    }
  } else {
    #pragma unroll
    for (int mi = 0; mi < 4; mi++) {
      int grow0 = bm * 128 + wm + mi * 16 + g * 4;
      #pragma unroll
      for (int ni = 0; ni < 4; ni++) {
        int gcol = bn * 128 + wn + ni * 16 + c;
        float bb = bias[gcol];
        #pragma unroll
        for (int r = 0; r < 4; r++)
          Cout[(size_t)(grow0 + r) * 1024 + gcol] = acc[mi][ni][r] + bb;
      }
    }
  }
}

// ---------------- K3: block-causal flash attention (v5) ----------------
// grid (64 b*h, 16 qtiles desc); 4 waves x 32 q-rows; kv tiles of 64.
// Swapped QK^T: S^T = mfma(K, Q) puts each q-row's P lane-local (q = lane&15)
// -> softmax has NO cross-lane ops on the common path and NO LDS P buffer.
// P -> PV A-fragments entirely in-register via permlane32/16_swap.
// LDS: K 2x8KB + V 2x8KB = 32KB; launch_bounds(256,4) -> 4 blocks/CU.
__global__ __launch_bounds__(256, 4) void k_attn(
    const u16* __restrict__ Qh, const u16* __restrict__ Kh,
    const u16* __restrict__ Vth,
    u16* __restrict__ Oh, u16* __restrict__ Ol) {
  __shared__ u16 lK[2][64 * 64], lV[2][64 * 64];
  const int t = threadIdx.x, lane = t & 63, w = t >> 6;
  const int bh = blockIdx.x;             // 0..63
  const int qt = 15 - blockIdx.y;        // longest blocks dispatched first
  const int b = bh >> 4, h = bh & 15;
  const int qrow0 = qt * 128;
  const int kvlen = (qt / 2 + 1) * 256;
  const int g = lane >> 4, c = lane & 15;

  // Q fragments for this wave's 32 rows (q on lane&15 as the B operand)
  bf16x8 qf[2][2];
  {
    const u16* qb = Qh + ((size_t)bh * 2048 + qrow0 + w * 32) * 64;
    #pragma unroll
    for (int mi = 0; mi < 2; mi++)
      #pragma unroll
      for (int ks = 0; ks < 2; ks++)
        qf[mi][ks] = *(const bf16x8*)(qb + (size_t)(mi * 16 + c) * 64 + ks * 32 + g * 8);
  }

  const u16* Kb = Kh + (size_t)bh * 2048 * 64;
  const u16* Vb = Vth + (size_t)bh * 64 * 2048;

  // staging: K [64 kv][64 d], Vt [64 d][64 kv]; source pre-swizzled (XOR by row)
  const int ci0 = t, ci1 = t + 256;
  const int r0 = ci0 >> 3, cc0 = ci0 & 7;
  const int r1 = ci1 >> 3, cc1 = ci1 & 7;
  const int cs0 = cc0 ^ (r0 & 7), cs1 = cc1 ^ (r1 & 7);

  // per-lane softmax state for q-row (mi*16 + c)
  float mrun[2] = {-INFINITY, -INFINITY}, lrun[2] = {0.f, 0.f};
  f32x4 o[2][4] = {};                    // rows q = mi*16 + g*4 + r, col d = di*16+c

  const int ntiles = kvlen >> 6;

  // prologue: stage tile 0 into buffer 0
  gl16(Kb + (size_t)r0 * 64 + cs0 * 8, lK[0] + (size_t)ci0 * 8);
  gl16(Vb + (size_t)r0 * 2048 + cs0 * 8, lV[0] + (size_t)ci0 * 8);
  gl16(Kb + (size_t)r1 * 64 + cs1 * 8, lK[0] + (size_t)ci1 * 8);
  gl16(Vb + (size_t)r1 * 2048 + cs1 * 8, lV[0] + (size_t)ci1 * 8);
  __syncthreads();

  for (int kt = 0; kt < ntiles; kt++) {
    const int cur = kt & 1, nxt = cur ^ 1;
    if (kt + 1 < ntiles) {               // prefetch next tile across compute
      const size_t kv0 = (size_t)(kt + 1) * 64;
      gl16(Kb + (kv0 + r0) * 64 + cs0 * 8, lK[nxt] + (size_t)ci0 * 8);
      gl16(Vb + (size_t)r0 * 2048 + kv0 + cs0 * 8, lV[nxt] + (size_t)ci0 * 8);
      gl16(Kb + (kv0 + r1) * 64 + cs1 * 8, lK[nxt] + (size_t)ci1 * 8);
      gl16(Vb + (size_t)r1 * 2048 + kv0 + cs1 * 8, lV[nxt] + (size_t)ci1 * 8);
    }

    // S^T[kv, q] = mfma(A=K, B=Q): lane holds S for q=mi*16+c, kv=ni*16+g*4+r
    f32x4 s[2][4] = {};
    __builtin_amdgcn_s_setprio(1);
    #pragma unroll
    for (int ni = 0; ni < 4; ni++) {
      int kr = ni * 16 + c;
      #pragma unroll
      for (int ks = 0; ks < 2; ks++) {
        int off = kr * 64 + ((ks * 4 + g) ^ (kr & 7)) * 8;
        bf16x8 kf = *(const bf16x8*)(lK[cur] + off);
        #pragma unroll
        for (int mi = 0; mi < 2; mi++)
          s[mi][ni] = __builtin_amdgcn_mfma_f32_16x16x32_bf16(kf, qf[mi][ks], s[mi][ni], 0, 0, 0);
      }
    }
    __builtin_amdgcn_s_setprio(0);

    // lane-local defer-max check (16 values per mi, all for q = mi*16+c)
    float tl[2];
    #pragma unroll
    for (int mi = 0; mi < 2; mi++) {
      float a0 = fmaxf(fmaxf(s[mi][0][0], s[mi][0][1]), fmaxf(s[mi][0][2], s[mi][0][3]));
      float a1 = fmaxf(fmaxf(s[mi][1][0], s[mi][1][1]), fmaxf(s[mi][1][2], s[mi][1][3]));
      float a2 = fmaxf(fmaxf(s[mi][2][0], s[mi][2][1]), fmaxf(s[mi][2][2], s[mi][2][3]));
      float a3 = fmaxf(fmaxf(s[mi][3][0], s[mi][3][1]), fmaxf(s[mi][3][2], s[mi][3][3]));
      tl[mi] = fmaxf(fmaxf(a0, a1), fmaxf(a2, a3));
    }
    float dmax = fmaxf(tl[0] - mrun[0], tl[1] - mrun[1]);
    if (!__all(dmax <= 8.0f)) {          // rare: first tile or large max jump
      #pragma unroll
      for (int mi = 0; mi < 2; mi++) {
        float tm = tl[mi];
        tm = fmaxf(tm, __shfl_xor(tm, 16));
        tm = fmaxf(tm, __shfl_xor(tm, 32));   // row max across the 4 g-lanes
        float mnew = fmaxf(mrun[mi], tm);
        float al = exp2f(mrun[mi] - mnew);
        mrun[mi] = mnew;
        lrun[mi] *= al;
        // o rows are q = mi*16 + g*4 + r -> fetch that row's alpha
        #pragma unroll
        for (int r = 0; r < 4; r++) {
          float ar = __shfl(al, g * 4 + r);
          #pragma unroll
          for (int di = 0; di < 4; di++) o[mi][di][r] *= ar;
        }
      }
    }

    // p = exp2(s - m); per-lane partial row-sum; pack + permlane -> PV A-frags
    bf16x8 pa[2][2];
    #pragma unroll
    for (int mi = 0; mi < 2; mi++) {
      #pragma unroll
      for (int ni = 0; ni < 4; ni++)
        #pragma unroll
        for (int r = 0; r < 4; r++)
          s[mi][ni][r] = exp2f(s[mi][ni][r] - mrun[mi]);
      #pragma unroll
      for (int ni = 0; ni < 4; ni++)
        lrun[mi] += (s[mi][ni][0] + s[mi][ni][1]) + (s[mi][ni][2] + s[mi][ni][3]);
      unsigned int Wd[4][2];
      #pragma unroll
      for (int ni = 0; ni < 4; ni++)
        #pragma unroll
        for (int rp = 0; rp < 2; rp++)
          Wd[ni][rp] = cvtpk(s[mi][ni][2 * rp], s[mi][ni][2 * rp + 1]);
      #pragma unroll
      for (int ks = 0; ks < 2; ks++) {
        unsigned int e0 = Wd[2 * ks][0], f0 = Wd[2 * ks + 1][0];
        unsigned int e1 = Wd[2 * ks][1], f1 = Wd[2 * ks + 1][1];
        asm volatile("v_permlane32_swap_b32 %0, %1" : "+v"(e0), "+v"(f0));
        asm volatile("v_permlane16_swap_b32 %0, %1" : "+v"(e0), "+v"(f0));
        asm volatile("v_permlane32_swap_b32 %0, %1" : "+v"(e1), "+v"(f1));
        asm volatile("v_permlane16_swap_b32 %0, %1" : "+v"(e1), "+v"(f1));
        union { u32x4 u; bf16x8 bv; } cvu;
        cvu.u = (u32x4){e0, e1, f0, f1};
        pa[mi][ks] = cvu.bv;             // P[q=c, kv=ks*32+g*8+j], j=0..7
      }
    }

    // PV: O += P * V
    __builtin_amdgcn_s_setprio(1);
    #pragma unroll
    for (int di = 0; di < 4; di++) {
      int vr = di * 16 + c;
      #pragma unroll
      for (int ks = 0; ks < 2; ks++) {
        int off = vr * 64 + ((ks * 4 + g) ^ (vr & 7)) * 8;
        bf16x8 vf = *(const bf16x8*)(lV[cur] + off);
        #pragma unroll
        for (int mi = 0; mi < 2; mi++)
          o[mi][di] = __builtin_amdgcn_mfma_f32_16x16x32_bf16(pa[mi][ks], vf, o[mi][di], 0, 0, 0);
      }
    }
    __builtin_amdgcn_s_setprio(0);

    // drains the prefetch (issued ~1k cycles ago) and fences buffer reuse
    __syncthreads();
  }

  // epilogue: full row-sum (across g-lanes), normalize, hi/lo split, write
  #pragma unroll
  for (int mi = 0; mi < 2; mi++) {
    float lf = lrun[mi];
    lf += __shfl_xor(lf, 16);
    lf += __shfl_xor(lf, 32);
    float inv = 1.0f / lf;               // for q = mi*16 + c
    #pragma unroll
    for (int r = 0; r < 4; r++) {
      float ir = __shfl(inv, g * 4 + r); // for q = mi*16 + g*4 + r
      int srow = qrow0 + w * 32 + mi * 16 + g * 4 + r;
      size_t rowo = ((size_t)b * 2048 + srow) * 1024 + h * 64;
      #pragma unroll
      for (int di = 0; di < 4; di++) {
        float v = o[mi][di][r] * ir;
        u16 hi = f2bf(v);
        Oh[rowo + di * 16 + c] = hi;
        Ol[rowo + di * 16 + c] = f2bf(v - bf2f(hi));
      }
    }
  }
}

// ---------------- launch ----------------
extern "C" void kernel_launch(void* const* d_in, const int* in_sizes, int n_in,
                              void* d_out, int out_size, void* d_ws, size_t ws_size,
                              hipStream_t stream) {
  const float* x     = (const float*)d_in[0];
  const float* gamma = (const float*)d_in[1];
  const float* beta  = (const float*)d_in[2];
  const float* Wqkv  = (const float*)d_in[3];
  const float* Wout  = (const float*)d_in[4];
  const float* bout  = (const float*)d_in[5];
  float* out = (float*)d_out;

  char* ws = (char*)d_ws;
  size_t off = 0;
  auto alloc = [&](size_t bytes) { char* p = ws + off; off += (bytes + 255) & ~(size_t)255; return p; };
  const size_t SZ_XN = (size_t)8192 * 1024 * 2;         // 16MB
  const size_t SZ_WQ = (size_t)3072 * 1024 * 2;         // 6MB
  const size_t SZ_WO = (size_t)1024 * 1024 * 2;         // 2MB
  const size_t SZ_QKV = (size_t)4 * 16 * 2048 * 64 * 2; // 16MB
  u16* xnh  = (u16*)alloc(SZ_XN);   // also attnout-hi after attention
  u16* xnl  = (u16*)alloc(SZ_XN);   // attnout-lo (written by k_attn)
  u16* wqth = (u16*)alloc(SZ_WQ);
  u16* wqtl = (u16*)alloc(SZ_WQ);
  u16* woth = (u16*)alloc(SZ_WO);
  u16* wotl = (u16*)alloc(SZ_WO);
  u16* Qh  = (u16*)alloc(SZ_QKV);
  u16* Kh  = (u16*)alloc(SZ_QKV);
  u16* Vth = (u16*)alloc(SZ_QKV);
  if (off > ws_size) return;  // workspace too small -> fail visibly (poisoned out)

  k_ln_split<<<8192, 256, 0, stream>>>(x, gamma, beta, xnh);
  k_wsplit_t<<<dim3(96, 32), 256, 0, stream>>>(Wqkv, wqth, wqtl, 1024, 3072);
  k_wsplit_t<<<dim3(32, 32), 256, 0, stream>>>(Wout, woth, wotl, 1024, 1024);
  k_gemm<0><<<dim3(64, 24), 256, 0, stream>>>(xnh, nullptr, wqth, wqtl,
                                              Qh, Kh, Vth, nullptr, nullptr);
  // attnout (hi/lo) reuses the xn buffers (xn is dead after the QKV GEMM)
  k_attn<<<dim3(64, 16), 256, 0, stream>>>(Qh, Kh, Vth, xnh, xnl);
  k_gemm<1><<<dim3(64, 8), 256, 0, stream>>>(xnh, xnl, woth, wotl,
                                             nullptr, nullptr, nullptr,
                                             out, bout);
}

// Round 6
// 223.045 us; speedup vs baseline: 1.4423x; 1.1511x over previous
//
#include <hip/hip_runtime.h>
#include <stdint.h>

typedef unsigned short u16;
typedef __attribute__((ext_vector_type(8))) short bf16x8;
typedef __attribute__((ext_vector_type(4))) float f32x4;
typedef __attribute__((ext_vector_type(4))) unsigned short u16x4;
typedef __attribute__((ext_vector_type(4))) unsigned int u32x4;

#define DEVI static __device__ __forceinline__

// dots*scale folded into Q, with base-2 softmax: exp(s) == exp2(s*log2e)
#define QSCALE (0.125f * 1.4426950408889634f)

DEVI u16 f2bf(float f) {
  union { float f; unsigned int u; } v; v.f = f;
  unsigned int u = v.u + 0x7fffu + ((v.u >> 16) & 1u);
  return (u16)(u >> 16);
}
DEVI float bf2f(u16 h) {
  union { unsigned int u; float f; } v; v.u = ((unsigned int)h) << 16;
  return v.f;
}
DEVI void gl16(const void* g, void* l) {
  __builtin_amdgcn_global_load_lds(
      (__attribute__((address_space(1))) void*)g,
      (__attribute__((address_space(3))) void*)l, 16, 0, 0);
}
// packed f32x2 -> bf16x2 (RNE), lo=bf16(a), hi=bf16(b)
DEVI unsigned int cvtpk(float a, float b) {
  unsigned int r;
  asm("v_cvt_pk_bf16_f32 %0, %1, %2" : "=v"(r) : "v"(a), "v"(b));
  return r;
}

// ---------------- K1: LayerNorm (hi only; QKV GEMM is 2-product) ----------------
__global__ __launch_bounds__(256) void k_ln_split(
    const float* __restrict__ x, const float* __restrict__ gamma,
    const float* __restrict__ beta, u16* __restrict__ xh) {
  const int row = blockIdx.x;          // 8192 rows
  const int t = threadIdx.x;           // 256 threads, 4 floats each
  const float4* xr = (const float4*)(x + (size_t)row * 1024);
  float4 v = xr[t];
  float s = v.x + v.y + v.z + v.w;
  float s2 = v.x * v.x + v.y * v.y + v.z * v.z + v.w * v.w;
  #pragma unroll
  for (int m = 1; m < 64; m <<= 1) { s += __shfl_xor(s, m); s2 += __shfl_xor(s2, m); }
  __shared__ float ls[4], ls2[4];
  if ((t & 63) == 0) { ls[t >> 6] = s; ls2[t >> 6] = s2; }
  __syncthreads();
  s = ls[0] + ls[1] + ls[2] + ls[3];
  s2 = ls2[0] + ls2[1] + ls2[2] + ls2[3];
  float mu = s * (1.0f / 1024.0f);
  float var = s2 * (1.0f / 1024.0f) - mu * mu;
  float rstd = rsqrtf(var + 1e-5f);
  float4 g = ((const float4*)gamma)[t];
  float4 b = ((const float4*)beta)[t];
  float xv[4] = {v.x, v.y, v.z, v.w};
  float gg[4] = {g.x, g.y, g.z, g.w};
  float bb[4] = {b.x, b.y, b.z, b.w};
  u16x4 hv;
  #pragma unroll
  for (int i = 0; i < 4; i++) {
    float xn = (xv[i] - mu) * rstd * gg[i] + bb[i];
    hv[i] = f2bf(xn);
  }
  ((u16x4*)xh)[(size_t)row * 256 + t] = hv;
}

// ---------------- K1b: transpose + hi/lo split of weights ----------------
// W [K][N] fp32  ->  Wt hi/lo [N][K] bf16
__global__ __launch_bounds__(256) void k_wsplit_t(
    const float* __restrict__ W, u16* __restrict__ Wth, u16* __restrict__ Wtl,
    int K, int N) {
  __shared__ float tile[32][33];
  const int t = threadIdx.x;
  const int tx = t & 31, ty = t >> 5;  // ty in 0..7
  #pragma unroll
  for (int i = 0; i < 4; i++) {
    int k = blockIdx.y * 32 + ty + i * 8;
    int n = blockIdx.x * 32 + tx;
    tile[ty + i * 8][tx] = W[(size_t)k * N + n];
  }
  __syncthreads();
  #pragma unroll
  for (int i = 0; i < 4; i++) {
    int n = blockIdx.x * 32 + ty + i * 8;   // output row
    int k = blockIdx.y * 32 + tx;           // output col
    float v = tile[tx][ty + i * 8];
    size_t o = (size_t)n * K + k;
    u16 hi = f2bf(v);
    Wth[o] = hi; Wtl[o] = f2bf(v - bf2f(hi));
  }
}

// ---------------- K2/K4: GEMM, BK=64 + XOR-swizzled LDS (conflict-free) ------
// C[M x N] = A[M x 1024] * Bt[N x 1024]^T.
// Tiles [128][64] u16 (128B rows, 8 chunks of 16B), staged with pre-swizzled
// source (cs = cc ^ (r&7)); frag reads use chunk = (ks*4+g) ^ (row&7) -- the
// k_attn pattern with measured-zero bank conflicts.
// MODE 0: A hi, B hi/lo (2 products) -> Q,K epilogue (scaled bf16 scatter)
// MODE 2: A hi, B hi    (1 product)  -> V epilogue (transposed bf16)
// MODE 1: A hi/lo, B hi/lo (3 products) -> out-proj epilogue (+bias, fp32)
template <int MODE>
__global__ __launch_bounds__(256) void k_gemm(
    const u16* __restrict__ Ah, const u16* __restrict__ Al,
    const u16* __restrict__ Bh, const u16* __restrict__ Bl,
    u16* __restrict__ Qh, u16* __restrict__ Kh, u16* __restrict__ Vth,
    float* __restrict__ Cout, const float* __restrict__ bias) {
  __shared__ u16 sAh[128 * 64];
  __shared__ u16 sBh[128 * 64];
  __shared__ u16 sBl[MODE != 2 ? 128 * 64 : 1];
  __shared__ u16 sAl[MODE == 1 ? 128 * 64 : 1];
  const int t = threadIdx.x, lane = t & 63, w = t >> 6;
  const int bm = blockIdx.x, bn = blockIdx.y;
  const int wm = (w >> 1) * 64, wn = (w & 1) * 64;
  const int g = lane >> 4, c = lane & 15;
  const size_t arow0 = (size_t)bm * 128, brow0 = (size_t)bn * 128;

  f32x4 acc[4][4] = {};

  for (int kt = 0; kt < 16; kt++) {
    __syncthreads();
    #pragma unroll
    for (int i = 0; i < 4; i++) {
      int ci = t + i * 256;              // 1024 chunks of 16B per tile
      int r = ci >> 3, cc = ci & 7;
      int cs = cc ^ (r & 7);
      size_t ka = (size_t)kt * 64 + cs * 8;
      gl16(Ah + (arow0 + r) * 1024 + ka, sAh + (size_t)ci * 8);
      gl16(Bh + (brow0 + r) * 1024 + ka, sBh + (size_t)ci * 8);
      if (MODE != 2) gl16(Bl + (brow0 + r) * 1024 + ka, sBl + (size_t)ci * 8);
      if (MODE == 1) gl16(Al + (arow0 + r) * 1024 + ka, sAl + (size_t)ci * 8);
    }
    __syncthreads();
    #pragma unroll
    for (int ks = 0; ks < 2; ks++) {     // two 32-wide K sub-steps per tile
      bf16x8 afh[4], afl[4], bfh[4], bfl[4];
      #pragma unroll
      for (int mi = 0; mi < 4; mi++) {
        int row = wm + mi * 16 + c;
        int off = row * 64 + (((ks * 4 + g) ^ (row & 7)) * 8);
        afh[mi] = *(const bf16x8*)(sAh + off);
        if (MODE == 1) afl[mi] = *(const bf16x8*)(sAl + off);
      }
      #pragma unroll
      for (int ni = 0; ni < 4; ni++) {
        int row = wn + ni * 16 + c;
        int off = row * 64 + (((ks * 4 + g) ^ (row & 7)) * 8);
        bfh[ni] = *(const bf16x8*)(sBh + off);
        if (MODE != 2) bfl[ni] = *(const bf16x8*)(sBl + off);
      }
      #pragma unroll
      for (int mi = 0; mi < 4; mi++)
        #pragma unroll
        for (int ni = 0; ni < 4; ni++) {
          acc[mi][ni] = __builtin_amdgcn_mfma_f32_16x16x32_bf16(afh[mi], bfh[ni], acc[mi][ni], 0, 0, 0);
          if (MODE != 2)
            acc[mi][ni] = __builtin_amdgcn_mfma_f32_16x16x32_bf16(afh[mi], bfl[ni], acc[mi][ni], 0, 0, 0);
          if (MODE == 1)
            acc[mi][ni] = __builtin_amdgcn_mfma_f32_16x16x32_bf16(afl[mi], bfh[ni], acc[mi][ni], 0, 0, 0);
        }
    }
  }

  if (MODE == 0) {                       // Q,K scatter (gcol < 2048)
    #pragma unroll
    for (int mi = 0; mi < 4; mi++) {
      int grow0 = bm * 128 + wm + mi * 16 + g * 4;   // m = b*2048+s
      int b = grow0 >> 11, s0 = grow0 & 2047;
      #pragma unroll
      for (int ni = 0; ni < 4; ni++) {
        int gcol = bn * 128 + wn + ni * 16 + c;       // n in [0,2048)
        int which = gcol >> 10, rem = gcol & 1023;
        int hh = rem >> 6, dd = rem & 63;
        u16* dh = which ? Kh : Qh;
        float sc = which ? 1.0f : QSCALE;
        #pragma unroll
        for (int r = 0; r < 4; r++) {
          size_t off = ((size_t)(b * 16 + hh) * 2048 + (s0 + r)) * 64 + dd;
          dh[off] = f2bf(acc[mi][ni][r] * sc);
        }
      }
    }
  } else if (MODE == 2) {                // V -> transposed [B,H,Dh,S]
    #pragma unroll
    for (int mi = 0; mi < 4; mi++) {
      int grow0 = bm * 128 + wm + mi * 16 + g * 4;
      int b = grow0 >> 11, s0 = grow0 & 2047;
      #pragma unroll
      for (int ni = 0; ni < 4; ni++) {
        int vcol = bn * 128 + wn + ni * 16 + c;       // 0..1023
        int hh = vcol >> 6, dd = vcol & 63;
        u16x4 hv;
        #pragma unroll
        for (int r = 0; r < 4; r++) hv[r] = f2bf(acc[mi][ni][r]);
        size_t off = ((size_t)((b * 16 + hh) * 64 + dd)) * 2048 + s0;
        *(u16x4*)(Vth + off) = hv;
      }
    }
  } else {                               // out-proj: +bias, fp32
    #pragma unroll
    for (int mi = 0; mi < 4; mi++) {
      int grow0 = bm * 128 + wm + mi * 16 + g * 4;
      #pragma unroll
      for (int ni = 0; ni < 4; ni++) {
        int gcol = bn * 128 + wn + ni * 16 + c;
        float bb = bias[gcol];
        #pragma unroll
        for (int r = 0; r < 4; r++)
          Cout[(size_t)(grow0 + r) * 1024 + gcol] = acc[mi][ni][r] + bb;
      }
    }
  }
}

// ---------------- K3: block-causal flash attention (v5) ----------------
// grid (64 b*h, 16 qtiles desc); 4 waves x 32 q-rows; kv tiles of 64.
// Swapped QK^T: S^T = mfma(K, Q) puts each q-row's P lane-local (q = lane&15)
// -> softmax has NO cross-lane ops on the common path and NO LDS P buffer.
// P -> PV A-fragments entirely in-register via permlane32/16_swap.
// LDS: K 2x8KB + V 2x8KB = 32KB; launch_bounds(256,4) -> 4 blocks/CU.
__global__ __launch_bounds__(256, 4) void k_attn(
    const u16* __restrict__ Qh, const u16* __restrict__ Kh,
    const u16* __restrict__ Vth,
    u16* __restrict__ Oh, u16* __restrict__ Ol) {
  __shared__ u16 lK[2][64 * 64], lV[2][64 * 64];
  const int t = threadIdx.x, lane = t & 63, w = t >> 6;
  const int bh = blockIdx.x;             // 0..63
  const int qt = 15 - blockIdx.y;        // longest blocks dispatched first
  const int b = bh >> 4, h = bh & 15;
  const int qrow0 = qt * 128;
  const int kvlen = (qt / 2 + 1) * 256;
  const int g = lane >> 4, c = lane & 15;

  // Q fragments for this wave's 32 rows (q on lane&15 as the B operand)
  bf16x8 qf[2][2];
  {
    const u16* qb = Qh + ((size_t)bh * 2048 + qrow0 + w * 32) * 64;
    #pragma unroll
    for (int mi = 0; mi < 2; mi++)
      #pragma unroll
      for (int ks = 0; ks < 2; ks++)
        qf[mi][ks] = *(const bf16x8*)(qb + (size_t)(mi * 16 + c) * 64 + ks * 32 + g * 8);
  }

  const u16* Kb = Kh + (size_t)bh * 2048 * 64;
  const u16* Vb = Vth + (size_t)bh * 64 * 2048;

  // staging: K [64 kv][64 d], Vt [64 d][64 kv]; source pre-swizzled (XOR by row)
  const int ci0 = t, ci1 = t + 256;
  const int r0 = ci0 >> 3, cc0 = ci0 & 7;
  const int r1 = ci1 >> 3, cc1 = ci1 & 7;
  const int cs0 = cc0 ^ (r0 & 7), cs1 = cc1 ^ (r1 & 7);

  // per-lane softmax state for q-row (mi*16 + c)
  float mrun[2] = {-INFINITY, -INFINITY}, lrun[2] = {0.f, 0.f};
  f32x4 o[2][4] = {};                    // rows q = mi*16 + g*4 + r, col d = di*16+c

  const int ntiles = kvlen >> 6;

  // prologue: stage tile 0 into buffer 0
  gl16(Kb + (size_t)r0 * 64 + cs0 * 8, lK[0] + (size_t)ci0 * 8);
  gl16(Vb + (size_t)r0 * 2048 + cs0 * 8, lV[0] + (size_t)ci0 * 8);
  gl16(Kb + (size_t)r1 * 64 + cs1 * 8, lK[0] + (size_t)ci1 * 8);
  gl16(Vb + (size_t)r1 * 2048 + cs1 * 8, lV[0] + (size_t)ci1 * 8);
  __syncthreads();

  for (int kt = 0; kt < ntiles; kt++) {
    const int cur = kt & 1, nxt = cur ^ 1;
    if (kt + 1 < ntiles) {               // prefetch next tile across compute
      const size_t kv0 = (size_t)(kt + 1) * 64;
      gl16(Kb + (kv0 + r0) * 64 + cs0 * 8, lK[nxt] + (size_t)ci0 * 8);
      gl16(Vb + (size_t)r0 * 2048 + kv0 + cs0 * 8, lV[nxt] + (size_t)ci0 * 8);
      gl16(Kb + (kv0 + r1) * 64 + cs1 * 8, lK[nxt] + (size_t)ci1 * 8);
      gl16(Vb + (size_t)r1 * 2048 + kv0 + cs1 * 8, lV[nxt] + (size_t)ci1 * 8);
    }

    // S^T[kv, q] = mfma(A=K, B=Q): lane holds S for q=mi*16+c, kv=ni*16+g*4+r
    f32x4 s[2][4] = {};
    __builtin_amdgcn_s_setprio(1);
    #pragma unroll
    for (int ni = 0; ni < 4; ni++) {
      int kr = ni * 16 + c;
      #pragma unroll
      for (int ks = 0; ks < 2; ks++) {
        int off = kr * 64 + ((ks * 4 + g) ^ (kr & 7)) * 8;
        bf16x8 kf = *(const bf16x8*)(lK[cur] + off);
        #pragma unroll
        for (int mi = 0; mi < 2; mi++)
          s[mi][ni] = __builtin_amdgcn_mfma_f32_16x16x32_bf16(kf, qf[mi][ks], s[mi][ni], 0, 0, 0);
      }
    }
    __builtin_amdgcn_s_setprio(0);

    // lane-local defer-max check (16 values per mi, all for q = mi*16+c)
    float tl[2];
    #pragma unroll
    for (int mi = 0; mi < 2; mi++) {
      float a0 = fmaxf(fmaxf(s[mi][0][0], s[mi][0][1]), fmaxf(s[mi][0][2], s[mi][0][3]));
      float a1 = fmaxf(fmaxf(s[mi][1][0], s[mi][1][1]), fmaxf(s[mi][1][2], s[mi][1][3]));
      float a2 = fmaxf(fmaxf(s[mi][2][0], s[mi][2][1]), fmaxf(s[mi][2][2], s[mi][2][3]));
      float a3 = fmaxf(fmaxf(s[mi][3][0], s[mi][3][1]), fmaxf(s[mi][3][2], s[mi][3][3]));
      tl[mi] = fmaxf(fmaxf(a0, a1), fmaxf(a2, a3));
    }
    float dmax = fmaxf(tl[0] - mrun[0], tl[1] - mrun[1]);
    if (!__all(dmax <= 8.0f)) {          // rare: first tile or large max jump
      #pragma unroll
      for (int mi = 0; mi < 2; mi++) {
        float tm = tl[mi];
        tm = fmaxf(tm, __shfl_xor(tm, 16));
        tm = fmaxf(tm, __shfl_xor(tm, 32));   // row max across the 4 g-lanes
        float mnew = fmaxf(mrun[mi], tm);
        float al = exp2f(mrun[mi] - mnew);
        mrun[mi] = mnew;
        lrun[mi] *= al;
        // o rows are q = mi*16 + g*4 + r -> fetch that row's alpha
        #pragma unroll
        for (int r = 0; r < 4; r++) {
          float ar = __shfl(al, g * 4 + r);
          #pragma unroll
          for (int di = 0; di < 4; di++) o[mi][di][r] *= ar;
        }
      }
    }

    // p = exp2(s - m); per-lane partial row-sum; pack + permlane -> PV A-frags
    bf16x8 pa[2][2];
    #pragma unroll
    for (int mi = 0; mi < 2; mi++) {
      #pragma unroll
      for (int ni = 0; ni < 4; ni++)
        #pragma unroll
        for (int r = 0; r < 4; r++)
          s[mi][ni][r] = exp2f(s[mi][ni][r] - mrun[mi]);
      #pragma unroll
      for (int ni = 0; ni < 4; ni++)
        lrun[mi] += (s[mi][ni][0] + s[mi][ni][1]) + (s[mi][ni][2] + s[mi][ni][3]);
      unsigned int Wd[4][2];
      #pragma unroll
      for (int ni = 0; ni < 4; ni++)
        #pragma unroll
        for (int rp = 0; rp < 2; rp++)
          Wd[ni][rp] = cvtpk(s[mi][ni][2 * rp], s[mi][ni][2 * rp + 1]);
      #pragma unroll
      for (int ks = 0; ks < 2; ks++) {
        unsigned int e0 = Wd[2 * ks][0], f0 = Wd[2 * ks + 1][0];
        unsigned int e1 = Wd[2 * ks][1], f1 = Wd[2 * ks + 1][1];
        asm volatile("v_permlane32_swap_b32 %0, %1" : "+v"(e0), "+v"(f0));
        asm volatile("v_permlane16_swap_b32 %0, %1" : "+v"(e0), "+v"(f0));
        asm volatile("v_permlane32_swap_b32 %0, %1" : "+v"(e1), "+v"(f1));
        asm volatile("v_permlane16_swap_b32 %0, %1" : "+v"(e1), "+v"(f1));
        union { u32x4 u; bf16x8 bv; } cvu;
        cvu.u = (u32x4){e0, e1, f0, f1};
        pa[mi][ks] = cvu.bv;             // P[q=c, kv=ks*32+g*8+j], j=0..7
      }
    }

    // PV: O += P * V
    __builtin_amdgcn_s_setprio(1);
    #pragma unroll
    for (int di = 0; di < 4; di++) {
      int vr = di * 16 + c;
      #pragma unroll
      for (int ks = 0; ks < 2; ks++) {
        int off = vr * 64 + ((ks * 4 + g) ^ (vr & 7)) * 8;
        bf16x8 vf = *(const bf16x8*)(lV[cur] + off);
        #pragma unroll
        for (int mi = 0; mi < 2; mi++)
          o[mi][di] = __builtin_amdgcn_mfma_f32_16x16x32_bf16(pa[mi][ks], vf, o[mi][di], 0, 0, 0);
      }
    }
    __builtin_amdgcn_s_setprio(0);

    // drains the prefetch (issued ~1k cycles ago) and fences buffer reuse
    __syncthreads();
  }

  // epilogue: full row-sum (across g-lanes), normalize, hi/lo split, write
  #pragma unroll
  for (int mi = 0; mi < 2; mi++) {
    float lf = lrun[mi];
    lf += __shfl_xor(lf, 16);
    lf += __shfl_xor(lf, 32);
    float inv = 1.0f / lf;               // for q = mi*16 + c
    #pragma unroll
    for (int r = 0; r < 4; r++) {
      float ir = __shfl(inv, g * 4 + r); // for q = mi*16 + g*4 + r
      int srow = qrow0 + w * 32 + mi * 16 + g * 4 + r;
      size_t rowo = ((size_t)b * 2048 + srow) * 1024 + h * 64;
      #pragma unroll
      for (int di = 0; di < 4; di++) {
        float v = o[mi][di][r] * ir;
        u16 hi = f2bf(v);
        Oh[rowo + di * 16 + c] = hi;
        Ol[rowo + di * 16 + c] = f2bf(v - bf2f(hi));
      }
    }
  }
}

// ---------------- launch ----------------
extern "C" void kernel_launch(void* const* d_in, const int* in_sizes, int n_in,
                              void* d_out, int out_size, void* d_ws, size_t ws_size,
                              hipStream_t stream) {
  const float* x     = (const float*)d_in[0];
  const float* gamma = (const float*)d_in[1];
  const float* beta  = (const float*)d_in[2];
  const float* Wqkv  = (const float*)d_in[3];
  const float* Wout  = (const float*)d_in[4];
  const float* bout  = (const float*)d_in[5];
  float* out = (float*)d_out;

  char* ws = (char*)d_ws;
  size_t off = 0;
  auto alloc = [&](size_t bytes) { char* p = ws + off; off += (bytes + 255) & ~(size_t)255; return p; };
  const size_t SZ_XN = (size_t)8192 * 1024 * 2;         // 16MB
  const size_t SZ_WQ = (size_t)3072 * 1024 * 2;         // 6MB
  const size_t SZ_WO = (size_t)1024 * 1024 * 2;         // 2MB
  const size_t SZ_QKV = (size_t)4 * 16 * 2048 * 64 * 2; // 16MB
  u16* xnh  = (u16*)alloc(SZ_XN);   // also attnout-hi after attention
  u16* xnl  = (u16*)alloc(SZ_XN);   // attnout-lo (written by k_attn)
  u16* wqth = (u16*)alloc(SZ_WQ);
  u16* wqtl = (u16*)alloc(SZ_WQ);
  u16* woth = (u16*)alloc(SZ_WO);
  u16* wotl = (u16*)alloc(SZ_WO);
  u16* Qh  = (u16*)alloc(SZ_QKV);
  u16* Kh  = (u16*)alloc(SZ_QKV);
  u16* Vth = (u16*)alloc(SZ_QKV);
  if (off > ws_size) return;  // workspace too small -> fail visibly (poisoned out)

  k_ln_split<<<8192, 256, 0, stream>>>(x, gamma, beta, xnh);
  k_wsplit_t<<<dim3(96, 32), 256, 0, stream>>>(Wqkv, wqth, wqtl, 1024, 3072);
  k_wsplit_t<<<dim3(32, 32), 256, 0, stream>>>(Wout, woth, wotl, 1024, 1024);
  // QKV projection, split: Q,K columns (2-product) and V columns (1-product)
  k_gemm<0><<<dim3(64, 16), 256, 0, stream>>>(xnh, nullptr, wqth, wqtl,
                                              Qh, Kh, nullptr, nullptr, nullptr);
  k_gemm<2><<<dim3(64, 8), 256, 0, stream>>>(xnh, nullptr, wqth + (size_t)2048 * 1024, nullptr,
                                             nullptr, nullptr, Vth, nullptr, nullptr);
  // attnout (hi/lo) reuses the xn buffers (xn is dead after the QKV GEMM)
  k_attn<<<dim3(64, 16), 256, 0, stream>>>(Qh, Kh, Vth, xnh, xnl);
  k_gemm<1><<<dim3(64, 8), 256, 0, stream>>>(xnh, xnl, woth, wotl,
                                             nullptr, nullptr, nullptr,
                                             out, bout);
}

// Round 7
// 207.259 us; speedup vs baseline: 1.5521x; 1.0762x over previous
//
#include <hip/hip_runtime.h>
#include <stdint.h>

typedef unsigned short u16;
typedef __attribute__((ext_vector_type(8))) short bf16x8;
typedef __attribute__((ext_vector_type(4))) float f32x4;
typedef __attribute__((ext_vector_type(4))) unsigned short u16x4;
typedef __attribute__((ext_vector_type(4))) unsigned int u32x4;

#define DEVI static __device__ __forceinline__

// dots*scale folded into Q, with base-2 softmax: exp(s) == exp2(s*log2e)
#define QSCALE (0.125f * 1.4426950408889634f)

DEVI u16 f2bf(float f) {
  union { float f; unsigned int u; } v; v.f = f;
  unsigned int u = v.u + 0x7fffu + ((v.u >> 16) & 1u);
  return (u16)(u >> 16);
}
DEVI float bf2f(u16 h) {
  union { unsigned int u; float f; } v; v.u = ((unsigned int)h) << 16;
  return v.f;
}
DEVI void gl16(const void* g, void* l) {
  __builtin_amdgcn_global_load_lds(
      (__attribute__((address_space(1))) void*)g,
      (__attribute__((address_space(3))) void*)l, 16, 0, 0);
}
// packed f32x2 -> bf16x2 (RNE), lo=bf16(a), hi=bf16(b)
DEVI unsigned int cvtpk(float a, float b) {
  unsigned int r;
  asm("v_cvt_pk_bf16_f32 %0, %1, %2" : "=v"(r) : "v"(a), "v"(b));
  return r;
}

// ---------------- K1: LayerNorm (hi only) ----------------
__global__ __launch_bounds__(256) void k_ln_split(
    const float* __restrict__ x, const float* __restrict__ gamma,
    const float* __restrict__ beta, u16* __restrict__ xh) {
  const int row = blockIdx.x;          // 8192 rows
  const int t = threadIdx.x;           // 256 threads, 4 floats each
  const float4* xr = (const float4*)(x + (size_t)row * 1024);
  float4 v = xr[t];
  float s = v.x + v.y + v.z + v.w;
  float s2 = v.x * v.x + v.y * v.y + v.z * v.z + v.w * v.w;
  #pragma unroll
  for (int m = 1; m < 64; m <<= 1) { s += __shfl_xor(s, m); s2 += __shfl_xor(s2, m); }
  __shared__ float ls[4], ls2[4];
  if ((t & 63) == 0) { ls[t >> 6] = s; ls2[t >> 6] = s2; }
  __syncthreads();
  s = ls[0] + ls[1] + ls[2] + ls[3];
  s2 = ls2[0] + ls2[1] + ls2[2] + ls2[3];
  float mu = s * (1.0f / 1024.0f);
  float var = s2 * (1.0f / 1024.0f) - mu * mu;
  float rstd = rsqrtf(var + 1e-5f);
  float4 g = ((const float4*)gamma)[t];
  float4 b = ((const float4*)beta)[t];
  float xv[4] = {v.x, v.y, v.z, v.w};
  float gg[4] = {g.x, g.y, g.z, g.w};
  float bb[4] = {b.x, b.y, b.z, b.w};
  u16x4 hv;
  #pragma unroll
  for (int i = 0; i < 4; i++) {
    float xn = (xv[i] - mu) * rstd * gg[i] + bb[i];
    hv[i] = f2bf(xn);
  }
  ((u16x4*)xh)[(size_t)row * 256 + t] = hv;
}

// ---------------- K1b: transpose + hi/lo split of weights ----------------
// W [K][N] fp32  ->  Wt hi/lo [N][K] bf16
__global__ __launch_bounds__(256) void k_wsplit_t(
    const float* __restrict__ W, u16* __restrict__ Wth, u16* __restrict__ Wtl,
    int K, int N) {
  __shared__ float tile[32][33];
  const int t = threadIdx.x;
  const int tx = t & 31, ty = t >> 5;  // ty in 0..7
  #pragma unroll
  for (int i = 0; i < 4; i++) {
    int k = blockIdx.y * 32 + ty + i * 8;
    int n = blockIdx.x * 32 + tx;
    tile[ty + i * 8][tx] = W[(size_t)k * N + n];
  }
  __syncthreads();
  #pragma unroll
  for (int i = 0; i < 4; i++) {
    int n = blockIdx.x * 32 + ty + i * 8;   // output row
    int k = blockIdx.y * 32 + tx;           // output col
    float v = tile[tx][ty + i * 8];
    size_t o = (size_t)n * K + k;
    u16 hi = f2bf(v);
    Wth[o] = hi; Wtl[o] = f2bf(v - bf2f(hi));
  }
}

// ---------------- K2/K4: GEMM, BK=64 + XOR-swizzled LDS (conflict-free) ------
// C[M x N] = A[M x 1024] * Bt[N x 1024]^T.  A is hi-only in all modes.
// MODE 0: B hi/lo (2 products) -> Q,K epilogue (scaled bf16 scatter)
// MODE 2: B hi    (1 product)  -> V epilogue (transposed bf16)
// MODE 1: B hi/lo (2 products) -> out-proj epilogue (+bias, fp32)
template <int MODE>
__global__ __launch_bounds__(256) void k_gemm(
    const u16* __restrict__ Ah,
    const u16* __restrict__ Bh, const u16* __restrict__ Bl,
    u16* __restrict__ Qh, u16* __restrict__ Kh, u16* __restrict__ Vth,
    float* __restrict__ Cout, const float* __restrict__ bias) {
  __shared__ u16 sAh[128 * 64];
  __shared__ u16 sBh[128 * 64];
  __shared__ u16 sBl[MODE != 2 ? 128 * 64 : 1];
  const int t = threadIdx.x, lane = t & 63, w = t >> 6;
  const int bm = blockIdx.x, bn = blockIdx.y;
  const int wm = (w >> 1) * 64, wn = (w & 1) * 64;
  const int g = lane >> 4, c = lane & 15;
  const size_t arow0 = (size_t)bm * 128, brow0 = (size_t)bn * 128;

  f32x4 acc[4][4] = {};

  for (int kt = 0; kt < 16; kt++) {
    __syncthreads();
    #pragma unroll
    for (int i = 0; i < 4; i++) {
      int ci = t + i * 256;              // 1024 chunks of 16B per tile
      int r = ci >> 3, cc = ci & 7;
      int cs = cc ^ (r & 7);
      size_t ka = (size_t)kt * 64 + cs * 8;
      gl16(Ah + (arow0 + r) * 1024 + ka, sAh + (size_t)ci * 8);
      gl16(Bh + (brow0 + r) * 1024 + ka, sBh + (size_t)ci * 8);
      if (MODE != 2) gl16(Bl + (brow0 + r) * 1024 + ka, sBl + (size_t)ci * 8);
    }
    __syncthreads();
    #pragma unroll
    for (int ks = 0; ks < 2; ks++) {     // two 32-wide K sub-steps per tile
      bf16x8 afh[4], bfh[4], bfl[4];
      #pragma unroll
      for (int mi = 0; mi < 4; mi++) {
        int row = wm + mi * 16 + c;
        int off = row * 64 + (((ks * 4 + g) ^ (row & 7)) * 8);
        afh[mi] = *(const bf16x8*)(sAh + off);
      }
      #pragma unroll
      for (int ni = 0; ni < 4; ni++) {
        int row = wn + ni * 16 + c;
        int off = row * 64 + (((ks * 4 + g) ^ (row & 7)) * 8);
        bfh[ni] = *(const bf16x8*)(sBh + off);
        if (MODE != 2) bfl[ni] = *(const bf16x8*)(sBl + off);
      }
      #pragma unroll
      for (int mi = 0; mi < 4; mi++)
        #pragma unroll
        for (int ni = 0; ni < 4; ni++) {
          acc[mi][ni] = __builtin_amdgcn_mfma_f32_16x16x32_bf16(afh[mi], bfh[ni], acc[mi][ni], 0, 0, 0);
          if (MODE != 2)
            acc[mi][ni] = __builtin_amdgcn_mfma_f32_16x16x32_bf16(afh[mi], bfl[ni], acc[mi][ni], 0, 0, 0);
        }
    }
  }

  if (MODE == 0) {                       // Q,K scatter (gcol < 2048)
    #pragma unroll
    for (int mi = 0; mi < 4; mi++) {
      int grow0 = bm * 128 + wm + mi * 16 + g * 4;   // m = b*2048+s
      int b = grow0 >> 11, s0 = grow0 & 2047;
      #pragma unroll
      for (int ni = 0; ni < 4; ni++) {
        int gcol = bn * 128 + wn + ni * 16 + c;       // n in [0,2048)
        int which = gcol >> 10, rem = gcol & 1023;
        int hh = rem >> 6, dd = rem & 63;
        u16* dh = which ? Kh : Qh;
        float sc = which ? 1.0f : QSCALE;
        #pragma unroll
        for (int r = 0; r < 4; r++) {
          size_t off = ((size_t)(b * 16 + hh) * 2048 + (s0 + r)) * 64 + dd;
          dh[off] = f2bf(acc[mi][ni][r] * sc);
        }
      }
    }
  } else if (MODE == 2) {                // V -> transposed [B,H,Dh,S]
    #pragma unroll
    for (int mi = 0; mi < 4; mi++) {
      int grow0 = bm * 128 + wm + mi * 16 + g * 4;
      int b = grow0 >> 11, s0 = grow0 & 2047;
      #pragma unroll
      for (int ni = 0; ni < 4; ni++) {
        int vcol = bn * 128 + wn + ni * 16 + c;       // 0..1023
        int hh = vcol >> 6, dd = vcol & 63;
        u16x4 hv;
        #pragma unroll
        for (int r = 0; r < 4; r++) hv[r] = f2bf(acc[mi][ni][r]);
        size_t off = ((size_t)((b * 16 + hh) * 64 + dd)) * 2048 + s0;
        *(u16x4*)(Vth + off) = hv;
      }
    }
  } else {                               // out-proj: +bias, fp32
    #pragma unroll
    for (int mi = 0; mi < 4; mi++) {
      int grow0 = bm * 128 + wm + mi * 16 + g * 4;
      #pragma unroll
      for (int ni = 0; ni < 4; ni++) {
        int gcol = bn * 128 + wn + ni * 16 + c;
        float bb = bias[gcol];
        #pragma unroll
        for (int r = 0; r < 4; r++)
          Cout[(size_t)(grow0 + r) * 1024 + gcol] = acc[mi][ni][r] + bb;
      }
    }
  }
}

// ---------------- K3: block-causal flash attention (v6) ----------------
// grid (64 b*h, 16 qtiles desc); 512 threads = 8 waves, 16 q-rows per wave.
// Swapped QK^T (lane-local softmax), in-register P via cvt_pk + permlane.
// 2 blocks/CU x 8 waves = 16 waves/CU; strength-reduced prefetch pointers.
__global__ __launch_bounds__(512, 4) void k_attn(
    const u16* __restrict__ Qh, const u16* __restrict__ Kh,
    const u16* __restrict__ Vth, u16* __restrict__ Oh) {
  __shared__ u16 lK[2][64 * 64], lV[2][64 * 64];
  const int t = threadIdx.x, lane = t & 63, w = t >> 6;  // 8 waves
  const int bh = blockIdx.x;             // 0..63
  const int qt = 15 - blockIdx.y;        // longest blocks dispatched first
  const int b = bh >> 4, h = bh & 15;
  const int qrow0 = qt * 128;
  const int kvlen = (qt / 2 + 1) * 256;
  const int g = lane >> 4, c = lane & 15;

  // Q fragments: wave w covers q-rows [qrow0 + w*16, +16); q = c as B-operand
  bf16x8 qf[2];
  {
    const u16* qb = Qh + ((size_t)bh * 2048 + qrow0 + w * 16) * 64;
    #pragma unroll
    for (int ks = 0; ks < 2; ks++)
      qf[ks] = *(const bf16x8*)(qb + (size_t)c * 64 + ks * 32 + g * 8);
  }

  const u16* Kb = Kh + (size_t)bh * 2048 * 64;
  const u16* Vb = Vth + (size_t)bh * 64 * 2048;

  // staging: 512 threads x 1 chunk each; source pre-swizzled (XOR by row)
  const int ci = t;
  const int r0 = ci >> 3, cc0 = ci & 7;
  const int cs0 = cc0 ^ (r0 & 7);

  // per-lane softmax state for q-row c
  float mrun = -INFINITY, lrun = 0.f;
  f32x4 o[4] = {};                       // rows q = g*4 + r, col d = di*16+c

  const int ntiles = kvlen >> 6;

  // prologue: stage tile 0 into buffer 0
  gl16(Kb + (size_t)r0 * 64 + cs0 * 8, lK[0] + (size_t)ci * 8);
  gl16(Vb + (size_t)r0 * 2048 + cs0 * 8, lV[0] + (size_t)ci * 8);
  __syncthreads();

  // prefetch pointers (tile 1), advanced by constant strides
  const u16* gK = Kb + (size_t)(64 + r0) * 64 + cs0 * 8;
  const u16* gV = Vb + (size_t)r0 * 2048 + 64 + cs0 * 8;

  for (int kt = 0; kt < ntiles; kt++) {
    const int cur = kt & 1, nxt = cur ^ 1;
    if (kt + 1 < ntiles) {               // prefetch next tile across compute
      gl16(gK, lK[nxt] + (size_t)ci * 8);  gK += 64 * 64;
      gl16(gV, lV[nxt] + (size_t)ci * 8);  gV += 64;
    }

    // S^T[kv, q] = mfma(A=K, B=Q): lane holds S for q=c, kv=ni*16+g*4+r
    f32x4 s[4] = {};
    __builtin_amdgcn_s_setprio(1);
    #pragma unroll
    for (int ni = 0; ni < 4; ni++) {
      int kr = ni * 16 + c;
      #pragma unroll
      for (int ks = 0; ks < 2; ks++) {
        int off = kr * 64 + ((ks * 4 + g) ^ (kr & 7)) * 8;
        bf16x8 kf = *(const bf16x8*)(lK[cur] + off);
        s[ni] = __builtin_amdgcn_mfma_f32_16x16x32_bf16(kf, qf[ks], s[ni], 0, 0, 0);
      }
    }
    __builtin_amdgcn_s_setprio(0);

    // lane-local defer-max check (16 values, all for q = c)
    float a0 = fmaxf(fmaxf(s[0][0], s[0][1]), fmaxf(s[0][2], s[0][3]));
    float a1 = fmaxf(fmaxf(s[1][0], s[1][1]), fmaxf(s[1][2], s[1][3]));
    float a2 = fmaxf(fmaxf(s[2][0], s[2][1]), fmaxf(s[2][2], s[2][3]));
    float a3 = fmaxf(fmaxf(s[3][0], s[3][1]), fmaxf(s[3][2], s[3][3]));
    float tl = fmaxf(fmaxf(a0, a1), fmaxf(a2, a3));
    if (!__all(tl - mrun <= 8.0f)) {     // rare: first tile or large max jump
      float tm = tl;
      tm = fmaxf(tm, __shfl_xor(tm, 16));
      tm = fmaxf(tm, __shfl_xor(tm, 32));  // row max across the 4 g-lanes
      float mnew = fmaxf(mrun, tm);
      float al = exp2f(mrun - mnew);
      mrun = mnew;
      lrun *= al;
      #pragma unroll
      for (int r = 0; r < 4; r++) {
        float ar = __shfl(al, g * 4 + r);  // alpha for o-row q = g*4+r
        #pragma unroll
        for (int di = 0; di < 4; di++) o[di][r] *= ar;
      }
    }

    // p = exp2(s - m); per-lane partial row-sum; pack + permlane -> PV A-frags
    #pragma unroll
    for (int ni = 0; ni < 4; ni++)
      #pragma unroll
      for (int r = 0; r < 4; r++)
        s[ni][r] = exp2f(s[ni][r] - mrun);
    #pragma unroll
    for (int ni = 0; ni < 4; ni++)
      lrun += (s[ni][0] + s[ni][1]) + (s[ni][2] + s[ni][3]);
    unsigned int Wd[4][2];
    #pragma unroll
    for (int ni = 0; ni < 4; ni++)
      #pragma unroll
      for (int rp = 0; rp < 2; rp++)
        Wd[ni][rp] = cvtpk(s[ni][2 * rp], s[ni][2 * rp + 1]);
    bf16x8 pa[2];
    #pragma unroll
    for (int ks = 0; ks < 2; ks++) {
      unsigned int e0 = Wd[2 * ks][0], f0 = Wd[2 * ks + 1][0];
      unsigned int e1 = Wd[2 * ks][1], f1 = Wd[2 * ks + 1][1];
      asm volatile("v_permlane32_swap_b32 %0, %1" : "+v"(e0), "+v"(f0));
      asm volatile("v_permlane16_swap_b32 %0, %1" : "+v"(e0), "+v"(f0));
      asm volatile("v_permlane32_swap_b32 %0, %1" : "+v"(e1), "+v"(f1));
      asm volatile("v_permlane16_swap_b32 %0, %1" : "+v"(e1), "+v"(f1));
      union { u32x4 u; bf16x8 bv; } cvu;
      cvu.u = (u32x4){e0, e1, f0, f1};
      pa[ks] = cvu.bv;                   // P[q=c, kv=ks*32+g*8+j], j=0..7
    }

    // PV: O += P * V
    __builtin_amdgcn_s_setprio(1);
    #pragma unroll
    for (int di = 0; di < 4; di++) {
      int vr = di * 16 + c;
      #pragma unroll
      for (int ks = 0; ks < 2; ks++) {
        int off = vr * 64 + ((ks * 4 + g) ^ (vr & 7)) * 8;
        bf16x8 vf = *(const bf16x8*)(lV[cur] + off);
        o[di] = __builtin_amdgcn_mfma_f32_16x16x32_bf16(pa[ks], vf, o[di], 0, 0, 0);
      }
    }
    __builtin_amdgcn_s_setprio(0);

    // drains the prefetch (issued ~1k cycles ago) and fences buffer reuse
    __syncthreads();
  }

  // epilogue: full row-sum (across g-lanes), normalize, write attnout bf16
  float lf = lrun;
  lf += __shfl_xor(lf, 16);
  lf += __shfl_xor(lf, 32);
  float inv = 1.0f / lf;                 // for q = c
  #pragma unroll
  for (int r = 0; r < 4; r++) {
    float ir = __shfl(inv, g * 4 + r);   // for q = g*4 + r
    int srow = qrow0 + w * 16 + g * 4 + r;
    size_t rowo = ((size_t)b * 2048 + srow) * 1024 + h * 64;
    #pragma unroll
    for (int di = 0; di < 4; di++)
      Oh[rowo + di * 16 + c] = f2bf(o[di][r] * ir);
  }
}

// ---------------- launch ----------------
extern "C" void kernel_launch(void* const* d_in, const int* in_sizes, int n_in,
                              void* d_out, int out_size, void* d_ws, size_t ws_size,
                              hipStream_t stream) {
  const float* x     = (const float*)d_in[0];
  const float* gamma = (const float*)d_in[1];
  const float* beta  = (const float*)d_in[2];
  const float* Wqkv  = (const float*)d_in[3];
  const float* Wout  = (const float*)d_in[4];
  const float* bout  = (const float*)d_in[5];
  float* out = (float*)d_out;

  char* ws = (char*)d_ws;
  size_t off = 0;
  auto alloc = [&](size_t bytes) { char* p = ws + off; off += (bytes + 255) & ~(size_t)255; return p; };
  const size_t SZ_XN = (size_t)8192 * 1024 * 2;         // 16MB
  const size_t SZ_WQ = (size_t)3072 * 1024 * 2;         // 6MB
  const size_t SZ_WO = (size_t)1024 * 1024 * 2;         // 2MB
  const size_t SZ_QKV = (size_t)4 * 16 * 2048 * 64 * 2; // 16MB
  u16* xnh  = (u16*)alloc(SZ_XN);   // also attnout (bf16) after attention
  u16* wqth = (u16*)alloc(SZ_WQ);
  u16* wqtl = (u16*)alloc(SZ_WQ);
  u16* woth = (u16*)alloc(SZ_WO);
  u16* wotl = (u16*)alloc(SZ_WO);
  u16* Qh  = (u16*)alloc(SZ_QKV);
  u16* Kh  = (u16*)alloc(SZ_QKV);
  u16* Vth = (u16*)alloc(SZ_QKV);
  if (off > ws_size) return;  // workspace too small -> fail visibly (poisoned out)

  k_ln_split<<<8192, 256, 0, stream>>>(x, gamma, beta, xnh);
  k_wsplit_t<<<dim3(96, 32), 256, 0, stream>>>(Wqkv, wqth, wqtl, 1024, 3072);
  k_wsplit_t<<<dim3(32, 32), 256, 0, stream>>>(Wout, woth, wotl, 1024, 1024);
  // QKV projection, split: Q,K columns (2-product) and V columns (1-product)
  k_gemm<0><<<dim3(64, 16), 256, 0, stream>>>(xnh, wqth, wqtl,
                                              Qh, Kh, nullptr, nullptr, nullptr);
  k_gemm<2><<<dim3(64, 8), 256, 0, stream>>>(xnh, wqth + (size_t)2048 * 1024, nullptr,
                                             nullptr, nullptr, Vth, nullptr, nullptr);
  // attnout (bf16) reuses the xn buffer (xn is dead after the QKV GEMMs)
  k_attn<<<dim3(64, 16), 512, 0, stream>>>(Qh, Kh, Vth, xnh);
  k_gemm<1><<<dim3(64, 8), 256, 0, stream>>>(xnh, woth, wotl,
                                             nullptr, nullptr, nullptr,
                                             out, bout);
}

// Round 8
// 180.184 us; speedup vs baseline: 1.7853x; 1.1503x over previous
//
#include <hip/hip_runtime.h>
#include <stdint.h>

typedef unsigned short u16;
typedef __attribute__((ext_vector_type(8))) short bf16x8;
typedef __attribute__((ext_vector_type(4))) float f32x4;
typedef __attribute__((ext_vector_type(4))) unsigned short u16x4;
typedef __attribute__((ext_vector_type(4))) unsigned int u32x4;

#define DEVI static __device__ __forceinline__

// dots*scale folded into Q, with base-2 softmax: exp(s) == exp2(s*log2e)
#define QSCALE (0.125f * 1.4426950408889634f)

DEVI u16 f2bf(float f) {
  union { float f; unsigned int u; } v; v.f = f;
  unsigned int u = v.u + 0x7fffu + ((v.u >> 16) & 1u);
  return (u16)(u >> 16);
}
DEVI void gl16(const void* g, void* l) {
  __builtin_amdgcn_global_load_lds(
      (__attribute__((address_space(1))) void*)g,
      (__attribute__((address_space(3))) void*)l, 16, 0, 0);
}
// packed f32x2 -> bf16x2 (RNE), lo=bf16(a), hi=bf16(b)
DEVI unsigned int cvtpk(float a, float b) {
  unsigned int r;
  asm("v_cvt_pk_bf16_f32 %0, %1, %2" : "=v"(r) : "v"(a), "v"(b));
  return r;
}

// attn load-balance: residue classes mod 4 of blockIdx.y each sum to 72 tiles
__device__ const int QTMAP[16] = {15, 14, 13, 12, 8, 9, 10, 11,
                                  5, 4, 6, 7, 2, 3, 1, 0};

// ---------------- K1: LayerNorm -> bf16 ----------------
__global__ __launch_bounds__(256) void k_ln_split(
    const float* __restrict__ x, const float* __restrict__ gamma,
    const float* __restrict__ beta, u16* __restrict__ xh) {
  const int row = blockIdx.x;          // 8192 rows
  const int t = threadIdx.x;           // 256 threads, 4 floats each
  const float4* xr = (const float4*)(x + (size_t)row * 1024);
  float4 v = xr[t];
  float s = v.x + v.y + v.z + v.w;
  float s2 = v.x * v.x + v.y * v.y + v.z * v.z + v.w * v.w;
  #pragma unroll
  for (int m = 1; m < 64; m <<= 1) { s += __shfl_xor(s, m); s2 += __shfl_xor(s2, m); }
  __shared__ float ls[4], ls2[4];
  if ((t & 63) == 0) { ls[t >> 6] = s; ls2[t >> 6] = s2; }
  __syncthreads();
  s = ls[0] + ls[1] + ls[2] + ls[3];
  s2 = ls2[0] + ls2[1] + ls2[2] + ls2[3];
  float mu = s * (1.0f / 1024.0f);
  float var = s2 * (1.0f / 1024.0f) - mu * mu;
  float rstd = rsqrtf(var + 1e-5f);
  float4 g = ((const float4*)gamma)[t];
  float4 b = ((const float4*)beta)[t];
  float xv[4] = {v.x, v.y, v.z, v.w};
  float gg[4] = {g.x, g.y, g.z, g.w};
  float bb[4] = {b.x, b.y, b.z, b.w};
  u16x4 hv;
  #pragma unroll
  for (int i = 0; i < 4; i++) {
    float xn = (xv[i] - mu) * rstd * gg[i] + bb[i];
    hv[i] = f2bf(xn);
  }
  ((u16x4*)xh)[(size_t)row * 256 + t] = hv;
}

// ---------------- K1b: transpose weights, fp32 -> bf16 ----------------
// W [K][N] fp32  ->  Wt [N][K] bf16
__global__ __launch_bounds__(256) void k_wsplit_t(
    const float* __restrict__ W, u16* __restrict__ Wth, int K, int N) {
  __shared__ float tile[32][33];
  const int t = threadIdx.x;
  const int tx = t & 31, ty = t >> 5;  // ty in 0..7
  #pragma unroll
  for (int i = 0; i < 4; i++) {
    int k = blockIdx.y * 32 + ty + i * 8;
    int n = blockIdx.x * 32 + tx;
    tile[ty + i * 8][tx] = W[(size_t)k * N + n];
  }
  __syncthreads();
  #pragma unroll
  for (int i = 0; i < 4; i++) {
    int n = blockIdx.x * 32 + ty + i * 8;   // output row
    int k = blockIdx.y * 32 + tx;           // output col
    Wth[(size_t)n * K + k] = f2bf(tile[tx][ty + i * 8]);
  }
}

// ---------------- K2/K4: bf16 GEMM, BK=64 + XOR-swizzled LDS ------
// C[M x N] = A[M x 1024] * Bt[N x 1024]^T, single product (pure bf16).
// MODE 0: QKV epilogue -- scatter Q (scaled), K, V-transposed, all bf16
// MODE 1: out-proj epilogue -- +bias, fp32 store
template <int MODE>
__global__ __launch_bounds__(256) void k_gemm(
    const u16* __restrict__ Ah, const u16* __restrict__ Bh,
    u16* __restrict__ Qh, u16* __restrict__ Kh, u16* __restrict__ Vth,
    float* __restrict__ Cout, const float* __restrict__ bias) {
  __shared__ u16 sAh[128 * 64];
  __shared__ u16 sBh[128 * 64];
  const int t = threadIdx.x, lane = t & 63, w = t >> 6;
  const int bm = blockIdx.x, bn = blockIdx.y;
  const int wm = (w >> 1) * 64, wn = (w & 1) * 64;
  const int g = lane >> 4, c = lane & 15;
  const size_t arow0 = (size_t)bm * 128, brow0 = (size_t)bn * 128;

  f32x4 acc[4][4] = {};

  for (int kt = 0; kt < 16; kt++) {
    __syncthreads();
    #pragma unroll
    for (int i = 0; i < 4; i++) {
      int ci = t + i * 256;              // 1024 chunks of 16B per tile
      int r = ci >> 3, cc = ci & 7;
      int cs = cc ^ (r & 7);
      size_t ka = (size_t)kt * 64 + cs * 8;
      gl16(Ah + (arow0 + r) * 1024 + ka, sAh + (size_t)ci * 8);
      gl16(Bh + (brow0 + r) * 1024 + ka, sBh + (size_t)ci * 8);
    }
    __syncthreads();
    #pragma unroll
    for (int ks = 0; ks < 2; ks++) {     // two 32-wide K sub-steps per tile
      bf16x8 afh[4], bfh[4];
      #pragma unroll
      for (int mi = 0; mi < 4; mi++) {
        int row = wm + mi * 16 + c;
        afh[mi] = *(const bf16x8*)(sAh + row * 64 + (((ks * 4 + g) ^ (row & 7)) * 8));
      }
      #pragma unroll
      for (int ni = 0; ni < 4; ni++) {
        int row = wn + ni * 16 + c;
        bfh[ni] = *(const bf16x8*)(sBh + row * 64 + (((ks * 4 + g) ^ (row & 7)) * 8));
      }
      #pragma unroll
      for (int mi = 0; mi < 4; mi++)
        #pragma unroll
        for (int ni = 0; ni < 4; ni++)
          acc[mi][ni] = __builtin_amdgcn_mfma_f32_16x16x32_bf16(afh[mi], bfh[ni], acc[mi][ni], 0, 0, 0);
    }
  }

  if (MODE == 0) {                       // QKV scatter
    #pragma unroll
    for (int mi = 0; mi < 4; mi++) {
      int grow0 = bm * 128 + wm + mi * 16 + g * 4;   // m = b*2048+s
      int b = grow0 >> 11, s0 = grow0 & 2047;
      #pragma unroll
      for (int ni = 0; ni < 4; ni++) {
        int gcol = bn * 128 + wn + ni * 16 + c;       // n in [0,3072)
        int which = gcol >> 10, rem = gcol & 1023;
        int hh = rem >> 6, dd = rem & 63;
        if (which == 2) {                              // V -> transposed [B,H,Dh,S]
          u16x4 hv;
          #pragma unroll
          for (int r = 0; r < 4; r++) hv[r] = f2bf(acc[mi][ni][r]);
          size_t off = ((size_t)((b * 16 + hh) * 64 + dd)) * 2048 + s0;
          *(u16x4*)(Vth + off) = hv;
        } else {                                       // Q or K -> [B,H,S,Dh]
          u16* dh = which ? Kh : Qh;
          float sc = which ? 1.0f : QSCALE;
          #pragma unroll
          for (int r = 0; r < 4; r++) {
            size_t off = ((size_t)(b * 16 + hh) * 2048 + (s0 + r)) * 64 + dd;
            dh[off] = f2bf(acc[mi][ni][r] * sc);
          }
        }
      }
    }
  } else {                               // out-proj: +bias, fp32
    #pragma unroll
    for (int mi = 0; mi < 4; mi++) {
      int grow0 = bm * 128 + wm + mi * 16 + g * 4;
      #pragma unroll
      for (int ni = 0; ni < 4; ni++) {
        int gcol = bn * 128 + wn + ni * 16 + c;
        float bb = bias[gcol];
        #pragma unroll
        for (int r = 0; r < 4; r++)
          Cout[(size_t)(grow0 + r) * 1024 + gcol] = acc[mi][ni][r] + bb;
      }
    }
  }
}

// ---------------- K3: block-causal flash attention (v7) ----------------
// grid (64 b*h, 16 qtiles via QTMAP); 512 threads = 8 waves, 16 q-rows/wave.
// Swapped QK^T (lane-local softmax), in-register P via cvt_pk + permlane.
// QTMAP balances tiles across CUs under round-robin block placement.
__global__ __launch_bounds__(512, 4) void k_attn(
    const u16* __restrict__ Qh, const u16* __restrict__ Kh,
    const u16* __restrict__ Vth, u16* __restrict__ Oh) {
  __shared__ u16 lK[2][64 * 64], lV[2][64 * 64];
  const int t = threadIdx.x, lane = t & 63, w = t >> 6;  // 8 waves
  const int bh = blockIdx.x;             // 0..63
  const int qt = QTMAP[blockIdx.y];
  const int b = bh >> 4, h = bh & 15;
  const int qrow0 = qt * 128;
  const int kvlen = (qt / 2 + 1) * 256;
  const int g = lane >> 4, c = lane & 15;

  // Q fragments: wave w covers q-rows [qrow0 + w*16, +16); q = c as B-operand
  bf16x8 qf[2];
  {
    const u16* qb = Qh + ((size_t)bh * 2048 + qrow0 + w * 16) * 64;
    #pragma unroll
    for (int ks = 0; ks < 2; ks++)
      qf[ks] = *(const bf16x8*)(qb + (size_t)c * 64 + ks * 32 + g * 8);
  }

  const u16* Kb = Kh + (size_t)bh * 2048 * 64;
  const u16* Vb = Vth + (size_t)bh * 64 * 2048;

  // staging: 512 threads x 1 chunk each; source pre-swizzled (XOR by row)
  const int ci = t;
  const int r0 = ci >> 3, cc0 = ci & 7;
  const int cs0 = cc0 ^ (r0 & 7);

  // per-lane softmax state for q-row c
  float mrun = -INFINITY, lrun = 0.f;
  f32x4 o[4] = {};                       // rows q = g*4 + r, col d = di*16+c

  const int ntiles = kvlen >> 6;

  // prologue: stage tile 0 into buffer 0
  gl16(Kb + (size_t)r0 * 64 + cs0 * 8, lK[0] + (size_t)ci * 8);
  gl16(Vb + (size_t)r0 * 2048 + cs0 * 8, lV[0] + (size_t)ci * 8);
  __syncthreads();

  // prefetch pointers (tile 1), advanced by constant strides
  const u16* gK = Kb + (size_t)(64 + r0) * 64 + cs0 * 8;
  const u16* gV = Vb + (size_t)r0 * 2048 + 64 + cs0 * 8;

  for (int kt = 0; kt < ntiles; kt++) {
    const int cur = kt & 1, nxt = cur ^ 1;
    if (kt + 1 < ntiles) {               // prefetch next tile across compute
      gl16(gK, lK[nxt] + (size_t)ci * 8);  gK += 64 * 64;
      gl16(gV, lV[nxt] + (size_t)ci * 8);  gV += 64;
    }

    // S^T[kv, q] = mfma(A=K, B=Q): lane holds S for q=c, kv=ni*16+g*4+r
    f32x4 s[4] = {};
    __builtin_amdgcn_s_setprio(1);
    #pragma unroll
    for (int ni = 0; ni < 4; ni++) {
      int kr = ni * 16 + c;
      #pragma unroll
      for (int ks = 0; ks < 2; ks++) {
        int off = kr * 64 + ((ks * 4 + g) ^ (kr & 7)) * 8;
        bf16x8 kf = *(const bf16x8*)(lK[cur] + off);
        s[ni] = __builtin_amdgcn_mfma_f32_16x16x32_bf16(kf, qf[ks], s[ni], 0, 0, 0);
      }
    }
    __builtin_amdgcn_s_setprio(0);

    // lane-local defer-max check (16 values, all for q = c)
    float a0 = fmaxf(fmaxf(s[0][0], s[0][1]), fmaxf(s[0][2], s[0][3]));
    float a1 = fmaxf(fmaxf(s[1][0], s[1][1]), fmaxf(s[1][2], s[1][3]));
    float a2 = fmaxf(fmaxf(s[2][0], s[2][1]), fmaxf(s[2][2], s[2][3]));
    float a3 = fmaxf(fmaxf(s[3][0], s[3][1]), fmaxf(s[3][2], s[3][3]));
    float tl = fmaxf(fmaxf(a0, a1), fmaxf(a2, a3));
    if (!__all(tl - mrun <= 8.0f)) {     // rare: first tile or large max jump
      float tm = tl;
      tm = fmaxf(tm, __shfl_xor(tm, 16));
      tm = fmaxf(tm, __shfl_xor(tm, 32));  // row max across the 4 g-lanes
      float mnew = fmaxf(mrun, tm);
      float al = exp2f(mrun - mnew);
      mrun = mnew;
      lrun *= al;
      #pragma unroll
      for (int r = 0; r < 4; r++) {
        float ar = __shfl(al, g * 4 + r);  // alpha for o-row q = g*4+r
        #pragma unroll
        for (int di = 0; di < 4; di++) o[di][r] *= ar;
      }
    }

    // p = exp2(s - m); per-lane partial row-sum; pack + permlane -> PV A-frags
    #pragma unroll
    for (int ni = 0; ni < 4; ni++)
      #pragma unroll
      for (int r = 0; r < 4; r++)
        s[ni][r] = exp2f(s[ni][r] - mrun);
    #pragma unroll
    for (int ni = 0; ni < 4; ni++)
      lrun += (s[ni][0] + s[ni][1]) + (s[ni][2] + s[ni][3]);
    unsigned int Wd[4][2];
    #pragma unroll
    for (int ni = 0; ni < 4; ni++)
      #pragma unroll
      for (int rp = 0; rp < 2; rp++)
        Wd[ni][rp] = cvtpk(s[ni][2 * rp], s[ni][2 * rp + 1]);
    bf16x8 pa[2];
    #pragma unroll
    for (int ks = 0; ks < 2; ks++) {
      unsigned int e0 = Wd[2 * ks][0], f0 = Wd[2 * ks + 1][0];
      unsigned int e1 = Wd[2 * ks][1], f1 = Wd[2 * ks + 1][1];
      asm volatile("v_permlane32_swap_b32 %0, %1" : "+v"(e0), "+v"(f0));
      asm volatile("v_permlane16_swap_b32 %0, %1" : "+v"(e0), "+v"(f0));
      asm volatile("v_permlane32_swap_b32 %0, %1" : "+v"(e1), "+v"(f1));
      asm volatile("v_permlane16_swap_b32 %0, %1" : "+v"(e1), "+v"(f1));
      union { u32x4 u; bf16x8 bv; } cvu;
      cvu.u = (u32x4){e0, e1, f0, f1};
      pa[ks] = cvu.bv;                   // P[q=c, kv=ks*32+g*8+j], j=0..7
    }

    // PV: O += P * V
    __builtin_amdgcn_s_setprio(1);
    #pragma unroll
    for (int di = 0; di < 4; di++) {
      int vr = di * 16 + c;
      #pragma unroll
      for (int ks = 0; ks < 2; ks++) {
        int off = vr * 64 + ((ks * 4 + g) ^ (vr & 7)) * 8;
        bf16x8 vf = *(const bf16x8*)(lV[cur] + off);
        o[di] = __builtin_amdgcn_mfma_f32_16x16x32_bf16(pa[ks], vf, o[di], 0, 0, 0);
      }
    }
    __builtin_amdgcn_s_setprio(0);

    // drains the prefetch (issued ~1k cycles ago) and fences buffer reuse
    __syncthreads();
  }

  // epilogue: full row-sum (across g-lanes), normalize, write attnout bf16
  float lf = lrun;
  lf += __shfl_xor(lf, 16);
  lf += __shfl_xor(lf, 32);
  float inv = 1.0f / lf;                 // for q = c
  #pragma unroll
  for (int r = 0; r < 4; r++) {
    float ir = __shfl(inv, g * 4 + r);   // for q = g*4 + r
    int srow = qrow0 + w * 16 + g * 4 + r;
    size_t rowo = ((size_t)b * 2048 + srow) * 1024 + h * 64;
    #pragma unroll
    for (int di = 0; di < 4; di++)
      Oh[rowo + di * 16 + c] = f2bf(o[di][r] * ir);
  }
}

// ---------------- launch ----------------
extern "C" void kernel_launch(void* const* d_in, const int* in_sizes, int n_in,
                              void* d_out, int out_size, void* d_ws, size_t ws_size,
                              hipStream_t stream) {
  const float* x     = (const float*)d_in[0];
  const float* gamma = (const float*)d_in[1];
  const float* beta  = (const float*)d_in[2];
  const float* Wqkv  = (const float*)d_in[3];
  const float* Wout  = (const float*)d_in[4];
  const float* bout  = (const float*)d_in[5];
  float* out = (float*)d_out;

  char* ws = (char*)d_ws;
  size_t off = 0;
  auto alloc = [&](size_t bytes) { char* p = ws + off; off += (bytes + 255) & ~(size_t)255; return p; };
  const size_t SZ_XN = (size_t)8192 * 1024 * 2;         // 16MB
  const size_t SZ_WQ = (size_t)3072 * 1024 * 2;         // 6MB
  const size_t SZ_WO = (size_t)1024 * 1024 * 2;         // 2MB
  const size_t SZ_QKV = (size_t)4 * 16 * 2048 * 64 * 2; // 16MB
  u16* xnh  = (u16*)alloc(SZ_XN);   // also attnout (bf16) after attention
  u16* wqth = (u16*)alloc(SZ_WQ);
  u16* woth = (u16*)alloc(SZ_WO);
  u16* Qh  = (u16*)alloc(SZ_QKV);
  u16* Kh  = (u16*)alloc(SZ_QKV);
  u16* Vth = (u16*)alloc(SZ_QKV);
  if (off > ws_size) return;  // workspace too small -> fail visibly (poisoned out)

  k_ln_split<<<8192, 256, 0, stream>>>(x, gamma, beta, xnh);
  k_wsplit_t<<<dim3(96, 32), 256, 0, stream>>>(Wqkv, wqth, 1024, 3072);
  k_wsplit_t<<<dim3(32, 32), 256, 0, stream>>>(Wout, woth, 1024, 1024);
  // QKV projection: one pure-bf16 GEMM over all 3072 columns
  k_gemm<0><<<dim3(64, 24), 256, 0, stream>>>(xnh, wqth,
                                              Qh, Kh, Vth, nullptr, nullptr);
  // attnout (bf16) reuses the xn buffer (xn is dead after the QKV GEMM)
  k_attn<<<dim3(64, 16), 512, 0, stream>>>(Qh, Kh, Vth, xnh);
  k_gemm<1><<<dim3(64, 8), 256, 0, stream>>>(xnh, woth,
                                             nullptr, nullptr, nullptr,
                                             out, bout);
}